// Round 1
// baseline (831.267 us; speedup 1.0000x reference)
//
#include <hip/hip_runtime.h>

#define NNODES 50000
#define NEDGES 800000
#define NCLASS 40

// ---------------- CSR build ----------------
__global__ __launch_bounds__(256) void k_count(const int* __restrict__ dst, int* __restrict__ cnt) {
    int e = blockIdx.x * 256 + threadIdx.x;
    atomicAdd(&cnt[dst[e]], 1);
}

__global__ __launch_bounds__(256) void k_dinv(const int* __restrict__ cnt, float* __restrict__ dinv) {
    int n = blockIdx.x * 256 + threadIdx.x;
    if (n < NNODES) dinv[n] = rsqrtf((float)cnt[n] + 1.0f);
}

__global__ __launch_bounds__(1024) void k_scan(const int* __restrict__ cnt, int* __restrict__ offsets) {
    __shared__ int part[1024];
    int t = threadIdx.x;
    const int CH = (NNODES + 1023) / 1024;  // 49
    int s = t * CH;
    int e = s + CH; if (e > NNODES) e = NNODES;
    int local = 0;
    for (int i = s; i < e; ++i) local += cnt[i];
    part[t] = local;
    __syncthreads();
    for (int d = 1; d < 1024; d <<= 1) {
        int v = (t >= d) ? part[t - d] : 0;
        __syncthreads();
        part[t] += v;
        __syncthreads();
    }
    int run = part[t] - local;  // exclusive prefix
    if (t == 0) offsets[0] = 0;
    for (int i = s; i < e; ++i) { run += cnt[i]; offsets[i + 1] = run; }
}

__global__ __launch_bounds__(256) void k_fill(const int* __restrict__ src, const int* __restrict__ dst,
                                              const int* __restrict__ offsets, int* __restrict__ cursor,
                                              int* __restrict__ esrc) {
    int e = blockIdx.x * 256 + threadIdx.x;
    int d = dst[e];
    int pos = atomicAdd(&cursor[d], 1);
    esrc[offsets[d] + pos] = src[e];
}

// ---------------- dense GEMM: C[M,128] = A[M,128] @ W[128,128] ----------------
__global__ __launch_bounds__(256) void k_gemm128(const float* __restrict__ A, const float* __restrict__ W,
                                                 float* __restrict__ C, int M) {
    __shared__ float As[16][68];   // transposed A tile, stride 68: 16B-aligned b128 reads, ~2-way max on writes
    __shared__ float Bs[16][128];
    int tid = threadIdx.x;
    int m0 = blockIdx.x * 64;
    int col_t = tid & 31;          // covers cols 4*col_t .. +3
    int row_t = tid >> 5;          // covers rows row_t*8 .. +7
    float acc[8][4];
#pragma unroll
    for (int i = 0; i < 8; ++i)
#pragma unroll
        for (int j = 0; j < 4; ++j) acc[i][j] = 0.f;

    int lr = tid >> 2;             // 0..63 (A-stage row)
    int lk = (tid & 3) << 2;       // 0,4,8,12
    int bk = tid >> 5;             // 0..7
    int bc = (tid & 31) << 2;

    for (int k0 = 0; k0 < 128; k0 += 16) {
        int gm = m0 + lr;
        float4 a4 = make_float4(0.f, 0.f, 0.f, 0.f);
        if (gm < M) a4 = *(const float4*)(A + gm * 128 + k0 + lk);
        As[lk + 0][lr] = a4.x; As[lk + 1][lr] = a4.y; As[lk + 2][lr] = a4.z; As[lk + 3][lr] = a4.w;
        *(float4*)&Bs[bk][bc]     = *(const float4*)(W + (k0 + bk) * 128 + bc);
        *(float4*)&Bs[bk + 8][bc] = *(const float4*)(W + (k0 + bk + 8) * 128 + bc);
        __syncthreads();
#pragma unroll
        for (int k = 0; k < 16; ++k) {
            float4 b4 = *(float4*)&Bs[k][col_t << 2];
            float4 al = *(float4*)&As[k][row_t << 3];
            float4 ah = *(float4*)&As[k][(row_t << 3) + 4];
            float a[8] = {al.x, al.y, al.z, al.w, ah.x, ah.y, ah.z, ah.w};
#pragma unroll
            for (int i = 0; i < 8; ++i) {
                acc[i][0] += a[i] * b4.x; acc[i][1] += a[i] * b4.y;
                acc[i][2] += a[i] * b4.z; acc[i][3] += a[i] * b4.w;
            }
        }
        __syncthreads();
    }
#pragma unroll
    for (int i = 0; i < 8; ++i) {
        int gm = m0 + (row_t << 3) + i;
        if (gm < M)
            *(float4*)(C + gm * 128 + (col_t << 2)) =
                make_float4(acc[i][0], acc[i][1], acc[i][2], acc[i][3]);
    }
}

// ---------------- edge aggregation: wave per node, CSR gather, no atomics ----------------
__global__ __launch_bounds__(256) void k_aggregate(const float* __restrict__ hW, const int* __restrict__ offsets,
                                                   const int* __restrict__ esrc, const float* __restrict__ dinv,
                                                   const float* __restrict__ bias, float* __restrict__ out) {
    __shared__ float bsh[128];
    int tid = threadIdx.x;
    if (tid < 128) bsh[tid] = bias[tid];
    __syncthreads();
    int lane = tid & 63, wave = tid >> 6;
    int n = blockIdx.x * 4 + wave;
    int beg = offsets[n], end = offsets[n + 1];
    float ax = 0.f, ay = 0.f;
    int c2 = lane * 2;
    for (int e = beg; e < end; ++e) {
        int s = esrc[e];                      // wave-uniform broadcast load
        float dv = dinv[s];
        float2 v = *(const float2*)(hW + s * 128 + c2);  // coalesced 512B/wave
        ax += v.x * dv; ay += v.y * dv;
    }
    float dn = dinv[n];
    float2 sv = *(const float2*)(hW + n * 128 + c2);
    float r0 = (ax + sv.x * dn) * dn + bsh[c2];
    float r1 = (ay + sv.y * dn) * dn + bsh[c2 + 1];
    *(float2*)(out + n * 128 + c2) = make_float2(fmaxf(r0, 0.f), fmaxf(r1, 0.f));
}

// ---------------- attention scores: scores[m]=a . tanh(H[m] @ W_att), m = n*4+l ----------------
__global__ __launch_bounds__(256) void k_attn(const float* __restrict__ h0, const float* __restrict__ h1,
                                              const float* __restrict__ h2, const float* __restrict__ h3,
                                              const float* __restrict__ W, const float* __restrict__ a_att,
                                              float* __restrict__ scores) {
    __shared__ float As[16][68];
    __shared__ float Bs[16][128];
    int tid = threadIdx.x;
    int m0 = blockIdx.x * 64;
    int col_t = tid & 31, row_t = tid >> 5;
    float acc[8][4];
#pragma unroll
    for (int i = 0; i < 8; ++i)
#pragma unroll
        for (int j = 0; j < 4; ++j) acc[i][j] = 0.f;

    int lr = tid >> 2;
    int lk = (tid & 3) << 2;
    int bk = tid >> 5;
    int bc = (tid & 31) << 2;
    int m = m0 + lr;                    // grid exact: m < 200000 always
    int nn = m >> 2, l = m & 3;
    const float* Ap = ((l & 2) ? ((l & 1) ? h3 : h2) : ((l & 1) ? h1 : h0)) + nn * 128;

    for (int k0 = 0; k0 < 128; k0 += 16) {
        float4 a4 = *(const float4*)(Ap + k0 + lk);
        As[lk + 0][lr] = a4.x; As[lk + 1][lr] = a4.y; As[lk + 2][lr] = a4.z; As[lk + 3][lr] = a4.w;
        *(float4*)&Bs[bk][bc]     = *(const float4*)(W + (k0 + bk) * 128 + bc);
        *(float4*)&Bs[bk + 8][bc] = *(const float4*)(W + (k0 + bk + 8) * 128 + bc);
        __syncthreads();
#pragma unroll
        for (int k = 0; k < 16; ++k) {
            float4 b4 = *(float4*)&Bs[k][col_t << 2];
            float4 al = *(float4*)&As[k][row_t << 3];
            float4 ah = *(float4*)&As[k][(row_t << 3) + 4];
            float a[8] = {al.x, al.y, al.z, al.w, ah.x, ah.y, ah.z, ah.w};
#pragma unroll
            for (int i = 0; i < 8; ++i) {
                acc[i][0] += a[i] * b4.x; acc[i][1] += a[i] * b4.y;
                acc[i][2] += a[i] * b4.z; acc[i][3] += a[i] * b4.w;
            }
        }
        __syncthreads();
    }
    float4 av = *(const float4*)(a_att + (col_t << 2));
#pragma unroll
    for (int i = 0; i < 8; ++i) {
        float p = av.x * tanhf(acc[i][0]) + av.y * tanhf(acc[i][1]) +
                  av.z * tanhf(acc[i][2]) + av.w * tanhf(acc[i][3]);
        // reduce across the 32 col-threads (lanes 0..31 and 32..63 are independent row groups)
        p += __shfl_xor(p, 16); p += __shfl_xor(p, 8); p += __shfl_xor(p, 4);
        p += __shfl_xor(p, 2);  p += __shfl_xor(p, 1);
        if (col_t == 0) scores[m0 + (row_t << 3) + i] = p;
    }
}

// ---------------- softmax over layers + fuse + output projection ----------------
__global__ __launch_bounds__(256) void k_fuse_out(const float* __restrict__ h0, const float* __restrict__ h1,
                                                  const float* __restrict__ h2, const float* __restrict__ h3,
                                                  const float* __restrict__ scores, const float* __restrict__ Wout,
                                                  const float* __restrict__ bout, float* __restrict__ out) {
    __shared__ float WoT[NCLASS * 132];   // transposed W_out: WoT[j*132 + c]
    __shared__ float bsh[NCLASS];
    __shared__ float fused[4][128];
    int tid = threadIdx.x;
    for (int idx = tid; idx < 128 * NCLASS; idx += 256) {
        int c = idx / NCLASS, j = idx % NCLASS;
        WoT[j * 132 + c] = Wout[idx];
    }
    if (tid < NCLASS) bsh[tid] = bout[tid];
    __syncthreads();

    int lane = tid & 63, wave = tid >> 6;
    int n = blockIdx.x * 4 + wave;
    float s0 = scores[n * 4 + 0], s1 = scores[n * 4 + 1];
    float s2 = scores[n * 4 + 2], s3 = scores[n * 4 + 3];
    float mx = fmaxf(fmaxf(s0, s1), fmaxf(s2, s3));
    float e0 = expf(s0 - mx), e1 = expf(s1 - mx), e2 = expf(s2 - mx), e3 = expf(s3 - mx);
    float inv = 1.0f / (e0 + e1 + e2 + e3);
    e0 *= inv; e1 *= inv; e2 *= inv; e3 *= inv;

    int c2 = lane * 2;
    const float2 v0 = *(const float2*)(h0 + n * 128 + c2);
    const float2 v1 = *(const float2*)(h1 + n * 128 + c2);
    const float2 v2 = *(const float2*)(h2 + n * 128 + c2);
    const float2 v3 = *(const float2*)(h3 + n * 128 + c2);
    float2 f;
    f.x = e0 * v0.x + e1 * v1.x + e2 * v2.x + e3 * v3.x;
    f.y = e0 * v0.y + e1 * v1.y + e2 * v2.y + e3 * v3.y;
    *(float2*)&fused[wave][c2] = f;   // same-wave LDS RAW: compiler inserts lgkmcnt wait

    if (lane < NCLASS) {
        float acc = bsh[lane];
#pragma unroll
        for (int k = 0; k < 128; k += 4) {
            float4 f4 = *(const float4*)&fused[wave][k];
            float4 w4 = *(const float4*)&WoT[lane * 132 + k];
            acc += f4.x * w4.x + f4.y * w4.y + f4.z * w4.z + f4.w * w4.w;
        }
        out[n * NCLASS + lane] = acc;
    }
}

extern "C" void kernel_launch(void* const* d_in, const int* in_sizes, int n_in,
                              void* d_out, int out_size, void* d_ws, size_t ws_size,
                              hipStream_t stream) {
    const float* x     = (const float*)d_in[0];
    const int*   ei    = (const int*)d_in[1];
    const float* convW = (const float*)d_in[2];
    const float* convb = (const float*)d_in[3];
    const float* W_att = (const float*)d_in[4];
    const float* a_att = (const float*)d_in[5];
    const float* W_out = (const float*)d_in[6];
    const float* b_out = (const float*)d_in[7];
    float* out = (float*)d_out;

    char* ws = (char*)d_ws;
    size_t off = 0;
    auto take = [&](size_t nbytes) { char* p = ws + off; off += (nbytes + 255) & ~(size_t)255; return p; };
    float* dinv    = (float*)take(NNODES * 4);
    int*   cnt     = (int*)take(NNODES * 4);
    int*   cursor  = (int*)take(NNODES * 4);
    int*   offsets = (int*)take((NNODES + 1) * 4);
    int*   esrc    = (int*)take(NEDGES * 4);
    float* scores  = (float*)take(NNODES * 4 * 4);
    float* hW      = (float*)take((size_t)NNODES * 128 * 4);
    float* hs[4];
    for (int l = 0; l < 4; ++l) hs[l] = (float*)take((size_t)NNODES * 128 * 4);

    const int* src = ei;
    const int* dst = ei + NEDGES;

    hipMemsetAsync(cnt, 0, NNODES * 4, stream);
    k_count<<<NEDGES / 256, 256, 0, stream>>>(dst, cnt);
    k_dinv<<<(NNODES + 255) / 256, 256, 0, stream>>>(cnt, dinv);
    k_scan<<<1, 1024, 0, stream>>>(cnt, offsets);
    hipMemsetAsync(cursor, 0, NNODES * 4, stream);
    k_fill<<<NEDGES / 256, 256, 0, stream>>>(src, dst, offsets, cursor, esrc);

    const float* hprev = x;
    for (int l = 0; l < 4; ++l) {
        k_gemm128<<<(NNODES + 63) / 64, 256, 0, stream>>>(hprev, convW + l * 128 * 128, hW, NNODES);
        k_aggregate<<<NNODES / 4, 256, 0, stream>>>(hW, offsets, esrc, dinv, convb + l * 128, hs[l]);
        hprev = hs[l];
    }
    k_attn<<<(NNODES * 4) / 64, 256, 0, stream>>>(hs[0], hs[1], hs[2], hs[3], W_att, a_att, scores);
    k_fuse_out<<<NNODES / 4, 256, 0, stream>>>(hs[0], hs[1], hs[2], hs[3], scores, W_out, b_out, out);
}

// Round 2
// 754.849 us; speedup vs baseline: 1.1012x; 1.1012x over previous
//
#include <hip/hip_runtime.h>

#define NNODES 50000
#define NEDGES 800000
#define NCLASS 40

typedef _Float16 half8  __attribute__((ext_vector_type(8)));
typedef _Float16 half4  __attribute__((ext_vector_type(4)));
typedef _Float16 half2v __attribute__((ext_vector_type(2)));
typedef float    floatx4 __attribute__((ext_vector_type(4)));

// ---------------- CSR build ----------------
__global__ __launch_bounds__(256) void k_count(const int* __restrict__ dst, int* __restrict__ cnt) {
    int e = blockIdx.x * 256 + threadIdx.x;
    atomicAdd(&cnt[dst[e]], 1);
}

__global__ __launch_bounds__(256) void k_dinv(const int* __restrict__ cnt, float* __restrict__ dinv) {
    int n = blockIdx.x * 256 + threadIdx.x;
    if (n < NNODES) dinv[n] = rsqrtf((float)cnt[n] + 1.0f);
}

__global__ __launch_bounds__(1024) void k_scan(const int* __restrict__ cnt, int* __restrict__ offsets) {
    __shared__ int part[1024];
    int t = threadIdx.x;
    const int CH = (NNODES + 1023) / 1024;  // 49
    int s = t * CH;
    int e = s + CH; if (e > NNODES) e = NNODES;
    int local = 0;
    for (int i = s; i < e; ++i) local += cnt[i];
    part[t] = local;
    __syncthreads();
    for (int d = 1; d < 1024; d <<= 1) {
        int v = (t >= d) ? part[t - d] : 0;
        __syncthreads();
        part[t] += v;
        __syncthreads();
    }
    int run = part[t] - local;  // exclusive prefix
    if (t == 0) offsets[0] = 0;
    for (int i = s; i < e; ++i) { run += cnt[i]; offsets[i + 1] = run; }
}

__global__ __launch_bounds__(256) void k_fill(const int* __restrict__ src, const int* __restrict__ dst,
                                              const int* __restrict__ offsets, int* __restrict__ cursor,
                                              int* __restrict__ esrc) {
    int e = blockIdx.x * 256 + threadIdx.x;
    int d = dst[e];
    int pos = atomicAdd(&cursor[d], 1);
    esrc[offsets[d] + pos] = src[e];
}

// ---------------- fp32 -> fp16 conversions ----------------
__global__ __launch_bounds__(256) void k_f2h(const float* __restrict__ in, _Float16* __restrict__ out, int n4) {
    int i = blockIdx.x * 256 + threadIdx.x;
    if (i < n4) {
        float4 v = *(const float4*)(in + i * 4);
        half4 o = {(_Float16)v.x, (_Float16)v.y, (_Float16)v.z, (_Float16)v.w};
        *(half4*)(out + i * 4) = o;
    }
}

// WT[mat][n][k] = W[mat][k][n], fp16. mats: convW 0..3, W_att = 4
__global__ __launch_bounds__(256) void k_prepw(const float* __restrict__ convW, const float* __restrict__ W_att,
                                               _Float16* __restrict__ WT) {
    int idx = blockIdx.x * 256 + threadIdx.x;   // 5*16384 total
    int mat = idx >> 14, rem = idx & 16383;
    int n = rem >> 7, k = rem & 127;
    const float* src = (mat < 4) ? (convW + mat * 16384) : W_att;
    WT[idx] = (_Float16)src[k * 128 + n];
}

// ---------------- GEMM: C[M,128] = A[M,128] @ W, fp16 in, fp16 out, fp32 acc ----------------
// A-frag layout (16x16x32): lane holds A[m = l&15][k = (l>>4)*8 + j]; B-frag: B[k][n = l&15] -> read from WT[n][k].
// C/D: col = l&15, row = (l>>4)*4 + reg  (guide §3, m89-verified)
__global__ __launch_bounds__(256) void k_gemm_f16(const _Float16* __restrict__ A, const _Float16* __restrict__ WT,
                                                  _Float16* __restrict__ C, int M) {
    __shared__ float Cs[64][132];
    int tid = threadIdx.x;
    int wave = tid >> 6, lane = tid & 63;
    int quad = lane >> 4, l15 = lane & 15;
    int m0 = blockIdx.x * 64;
    int ko = quad * 8;

    floatx4 acc[4][2];
#pragma unroll
    for (int rt = 0; rt < 4; ++rt)
#pragma unroll
        for (int ct = 0; ct < 2; ++ct) acc[rt][ct] = (floatx4){0.f, 0.f, 0.f, 0.f};

#pragma unroll
    for (int kk = 0; kk < 4; ++kk) {
        half8 a[4], b[2];
#pragma unroll
        for (int rt = 0; rt < 4; ++rt) {
            int row = m0 + rt * 16 + l15;
            if (row > M - 1) row = M - 1;
            a[rt] = *(const half8*)(A + row * 128 + kk * 32 + ko);
        }
#pragma unroll
        for (int ct = 0; ct < 2; ++ct) {
            int n = wave * 32 + ct * 16 + l15;
            b[ct] = *(const half8*)(WT + n * 128 + kk * 32 + ko);
        }
#pragma unroll
        for (int rt = 0; rt < 4; ++rt)
#pragma unroll
            for (int ct = 0; ct < 2; ++ct)
                acc[rt][ct] = __builtin_amdgcn_mfma_f32_16x16x32_f16(a[rt], b[ct], acc[rt][ct], 0, 0, 0);
    }

    // epilogue: bounce through LDS to emit coalesced fp16 rows
#pragma unroll
    for (int rt = 0; rt < 4; ++rt)
#pragma unroll
        for (int ct = 0; ct < 2; ++ct)
#pragma unroll
            for (int r = 0; r < 4; ++r)
                Cs[rt * 16 + quad * 4 + r][wave * 32 + ct * 16 + l15] = acc[rt][ct][r];
    __syncthreads();
    int row = tid >> 2, seg = tid & 3;
    int gm = m0 + row;
    if (gm < M) {
#pragma unroll
        for (int j = 0; j < 4; ++j) {
            float4 f0 = *(const float4*)&Cs[row][seg * 32 + j * 8];
            float4 f1 = *(const float4*)&Cs[row][seg * 32 + j * 8 + 4];
            half8 o = {(_Float16)f0.x, (_Float16)f0.y, (_Float16)f0.z, (_Float16)f0.w,
                       (_Float16)f1.x, (_Float16)f1.y, (_Float16)f1.z, (_Float16)f1.w};
            *(half8*)(C + gm * 128 + seg * 32 + j * 8) = o;
        }
    }
}

// ---------------- edge aggregation: wave per node, fp16 gather, fp32 math, fp16 out ----------------
__global__ __launch_bounds__(256) void k_aggregate(const _Float16* __restrict__ hW, const int* __restrict__ offsets,
                                                   const int* __restrict__ esrc, const float* __restrict__ dinv,
                                                   const float* __restrict__ bias, _Float16* __restrict__ outh) {
    __shared__ float bsh[128];
    int tid = threadIdx.x;
    if (tid < 128) bsh[tid] = bias[tid];
    __syncthreads();
    int lane = tid & 63, wave = tid >> 6;
    int n = blockIdx.x * 4 + wave;
    int beg = offsets[n], end = offsets[n + 1];
    float ax = 0.f, ay = 0.f;
    int c2 = lane * 2;
    for (int e = beg; e < end; ++e) {
        int s = esrc[e];                                  // wave-uniform broadcast load
        float dv = dinv[s];
        half2v v = *(const half2v*)(hW + s * 128 + c2);   // 256B/wave coalesced gather
        ax += (float)v.x * dv; ay += (float)v.y * dv;
    }
    float dn = dinv[n];
    half2v sv = *(const half2v*)(hW + n * 128 + c2);
    float r0 = (ax + (float)sv.x * dn) * dn + bsh[c2];
    float r1 = (ay + (float)sv.y * dn) * dn + bsh[c2 + 1];
    half2v o = {(_Float16)fmaxf(r0, 0.f), (_Float16)fmaxf(r1, 0.f)};
    *(half2v*)(outh + n * 128 + c2) = o;
}

// ---------------- attention scores via MFMA: scores[m] = a . tanh(H[m] @ W_att), m = n*4+l ----------------
__global__ __launch_bounds__(256) void k_attn(const _Float16* __restrict__ h0, const _Float16* __restrict__ h1,
                                              const _Float16* __restrict__ h2, const _Float16* __restrict__ h3,
                                              const _Float16* __restrict__ WT, const float* __restrict__ a_att,
                                              float* __restrict__ scores) {
    int tid = threadIdx.x;
    int wave = tid >> 6, lane = tid & 63;
    int quad = lane >> 4, l15 = lane & 15;
    int mw = blockIdx.x * 64 + wave * 16;     // 16 rows per wave; M=200000 exact
    int m = mw + l15;
    int layer = m & 3, node = m >> 2;
    const _Float16* hb = (layer & 2) ? ((layer & 1) ? h3 : h2) : ((layer & 1) ? h1 : h0);
    const _Float16* Ap = hb + node * 128 + quad * 8;
    half8 a[4];
#pragma unroll
    for (int kk = 0; kk < 4; ++kk) a[kk] = *(const half8*)(Ap + kk * 32);

    float p[4] = {0.f, 0.f, 0.f, 0.f};
#pragma unroll
    for (int ct = 0; ct < 8; ++ct) {
        int n = ct * 16 + l15;
        const _Float16* Bp = WT + n * 128 + quad * 8;
        floatx4 acc = (floatx4){0.f, 0.f, 0.f, 0.f};
#pragma unroll
        for (int kk = 0; kk < 4; ++kk)
            acc = __builtin_amdgcn_mfma_f32_16x16x32_f16(a[kk], *(const half8*)(Bp + kk * 32), acc, 0, 0, 0);
        float av = a_att[n];
#pragma unroll
        for (int r = 0; r < 4; ++r) p[r] += av * tanhf(acc[r]);
    }
#pragma unroll
    for (int r = 0; r < 4; ++r) {
        p[r] += __shfl_xor(p[r], 1); p[r] += __shfl_xor(p[r], 2);
        p[r] += __shfl_xor(p[r], 4); p[r] += __shfl_xor(p[r], 8);
    }
    if (l15 == 0) {
#pragma unroll
        for (int r = 0; r < 4; ++r) scores[mw + quad * 4 + r] = p[r];
    }
}

// ---------------- softmax over layers + fuse + output projection (fp32 math, fp16 h reads) ----------------
__global__ __launch_bounds__(256) void k_fuse_out(const _Float16* __restrict__ h0, const _Float16* __restrict__ h1,
                                                  const _Float16* __restrict__ h2, const _Float16* __restrict__ h3,
                                                  const float* __restrict__ scores, const float* __restrict__ Wout,
                                                  const float* __restrict__ bout, float* __restrict__ out) {
    __shared__ float WoT[NCLASS * 132];   // transposed W_out: WoT[j*132 + c]
    __shared__ float bsh[NCLASS];
    __shared__ float fused[4][128];
    int tid = threadIdx.x;
    for (int idx = tid; idx < 128 * NCLASS; idx += 256) {
        int c = idx / NCLASS, j = idx % NCLASS;
        WoT[j * 132 + c] = Wout[idx];
    }
    if (tid < NCLASS) bsh[tid] = bout[tid];
    __syncthreads();

    int lane = tid & 63, wave = tid >> 6;
    int n = blockIdx.x * 4 + wave;
    float s0 = scores[n * 4 + 0], s1 = scores[n * 4 + 1];
    float s2 = scores[n * 4 + 2], s3 = scores[n * 4 + 3];
    float mx = fmaxf(fmaxf(s0, s1), fmaxf(s2, s3));
    float e0 = expf(s0 - mx), e1 = expf(s1 - mx), e2 = expf(s2 - mx), e3 = expf(s3 - mx);
    float inv = 1.0f / (e0 + e1 + e2 + e3);
    e0 *= inv; e1 *= inv; e2 *= inv; e3 *= inv;

    int c2 = lane * 2;
    half2v v0 = *(const half2v*)(h0 + n * 128 + c2);
    half2v v1 = *(const half2v*)(h1 + n * 128 + c2);
    half2v v2 = *(const half2v*)(h2 + n * 128 + c2);
    half2v v3 = *(const half2v*)(h3 + n * 128 + c2);
    float2 f;
    f.x = e0 * (float)v0.x + e1 * (float)v1.x + e2 * (float)v2.x + e3 * (float)v3.x;
    f.y = e0 * (float)v0.y + e1 * (float)v1.y + e2 * (float)v2.y + e3 * (float)v3.y;
    *(float2*)&fused[wave][c2] = f;   // same-wave LDS RAW: compiler inserts lgkmcnt wait

    if (lane < NCLASS) {
        float acc = bsh[lane];
#pragma unroll
        for (int k = 0; k < 128; k += 4) {
            float4 f4 = *(const float4*)&fused[wave][k];
            float4 w4 = *(const float4*)&WoT[lane * 132 + k];
            acc += f4.x * w4.x + f4.y * w4.y + f4.z * w4.z + f4.w * w4.w;
        }
        out[n * NCLASS + lane] = acc;
    }
}

extern "C" void kernel_launch(void* const* d_in, const int* in_sizes, int n_in,
                              void* d_out, int out_size, void* d_ws, size_t ws_size,
                              hipStream_t stream) {
    const float* x     = (const float*)d_in[0];
    const int*   ei    = (const int*)d_in[1];
    const float* convW = (const float*)d_in[2];
    const float* convb = (const float*)d_in[3];
    const float* W_att = (const float*)d_in[4];
    const float* a_att = (const float*)d_in[5];
    const float* W_out = (const float*)d_in[6];
    const float* b_out = (const float*)d_in[7];
    float* out = (float*)d_out;

    char* ws = (char*)d_ws;
    size_t off = 0;
    auto take = [&](size_t nbytes) { char* p = ws + off; off += (nbytes + 255) & ~(size_t)255; return p; };
    float*     dinv    = (float*)take(NNODES * 4);
    int*       cnt     = (int*)take(NNODES * 4);
    int*       cursor  = (int*)take(NNODES * 4);
    int*       offsets = (int*)take((NNODES + 1) * 4);
    int*       esrc    = (int*)take(NEDGES * 4);
    float*     scores  = (float*)take(NNODES * 4 * 4);
    _Float16*  xh      = (_Float16*)take((size_t)NNODES * 128 * 2);
    _Float16*  WT      = (_Float16*)take((size_t)5 * 128 * 128 * 2);
    _Float16*  hW      = (_Float16*)take((size_t)NNODES * 128 * 2);
    _Float16*  hh[4];
    for (int l = 0; l < 4; ++l) hh[l] = (_Float16*)take((size_t)NNODES * 128 * 2);

    const int* src = ei;
    const int* dst = ei + NEDGES;

    hipMemsetAsync(cnt, 0, NNODES * 4, stream);
    k_count<<<NEDGES / 256, 256, 0, stream>>>(dst, cnt);
    k_dinv<<<(NNODES + 255) / 256, 256, 0, stream>>>(cnt, dinv);
    k_scan<<<1, 1024, 0, stream>>>(cnt, offsets);
    hipMemsetAsync(cursor, 0, NNODES * 4, stream);
    k_fill<<<NEDGES / 256, 256, 0, stream>>>(src, dst, offsets, cursor, esrc);

    k_f2h<<<(NNODES * 128 / 4 + 255) / 256, 256, 0, stream>>>(x, xh, NNODES * 128 / 4);
    k_prepw<<<(5 * 16384) / 256, 256, 0, stream>>>(convW, W_att, WT);

    const _Float16* hprev = xh;
    for (int l = 0; l < 4; ++l) {
        k_gemm_f16<<<(NNODES + 63) / 64, 256, 0, stream>>>(hprev, WT + l * 16384, hW, NNODES);
        k_aggregate<<<NNODES / 4, 256, 0, stream>>>(hW, offsets, esrc, dinv, convb + l * 128, hh[l]);
        hprev = hh[l];
    }
    k_attn<<<(NNODES * 4) / 64, 256, 0, stream>>>(hh[0], hh[1], hh[2], hh[3], WT + 4 * 16384, a_att, scores);
    k_fuse_out<<<NNODES / 4, 256, 0, stream>>>(hh[0], hh[1], hh[2], hh[3], scores, W_out, b_out, out);
}

// Round 3
// 580.926 us; speedup vs baseline: 1.4309x; 1.2994x over previous
//
#include <hip/hip_runtime.h>

#define NNODES 50000
#define NEDGES 800000
#define NCLASS 40

typedef _Float16 half8  __attribute__((ext_vector_type(8)));
typedef _Float16 half4  __attribute__((ext_vector_type(4)));
typedef _Float16 half2v __attribute__((ext_vector_type(2)));
typedef float    floatx4 __attribute__((ext_vector_type(4)));

__device__ __forceinline__ float fast_tanh(float x) {
    // 1 - 2/(e^{2x}+1): exact saturation at +/-inf, ~1e-6 rel err via v_exp_f32
    return 1.0f - 2.0f / (__expf(2.0f * x) + 1.0f);
}

// ---------------- CSR build ----------------
__global__ __launch_bounds__(256) void k_count(const int* __restrict__ dst, int* __restrict__ cnt) {
    int e = blockIdx.x * 256 + threadIdx.x;
    atomicAdd(&cnt[dst[e]], 1);
}

__global__ __launch_bounds__(256) void k_dinv(const int* __restrict__ cnt, float* __restrict__ dinv) {
    int n = blockIdx.x * 256 + threadIdx.x;
    if (n < NNODES) dinv[n] = rsqrtf((float)cnt[n] + 1.0f);
}

__global__ __launch_bounds__(1024) void k_scan(const int* __restrict__ cnt, int* __restrict__ offsets) {
    __shared__ int part[1024];
    int t = threadIdx.x;
    const int CH = (NNODES + 1023) / 1024;  // 49
    int s = t * CH;
    int e = s + CH; if (e > NNODES) e = NNODES;
    int local = 0;
    for (int i = s; i < e; ++i) local += cnt[i];
    part[t] = local;
    __syncthreads();
    for (int d = 1; d < 1024; d <<= 1) {
        int v = (t >= d) ? part[t - d] : 0;
        __syncthreads();
        part[t] += v;
        __syncthreads();
    }
    int run = part[t] - local;  // exclusive prefix
    if (t == 0) offsets[0] = 0;
    for (int i = s; i < e; ++i) { run += cnt[i]; offsets[i + 1] = run; }
}

__global__ __launch_bounds__(256) void k_fill(const int* __restrict__ src, const int* __restrict__ dst,
                                              const int* __restrict__ offsets, int* __restrict__ cursor,
                                              int* __restrict__ esrc) {
    int e = blockIdx.x * 256 + threadIdx.x;
    int d = dst[e];
    int pos = atomicAdd(&cursor[d], 1);
    esrc[offsets[d] + pos] = src[e];
}

// ---------------- fp32 -> fp16 conversions ----------------
__global__ __launch_bounds__(256) void k_f2h(const float* __restrict__ in, _Float16* __restrict__ out, int n4) {
    int i = blockIdx.x * 256 + threadIdx.x;
    if (i < n4) {
        float4 v = *(const float4*)(in + i * 4);
        half4 o = {(_Float16)v.x, (_Float16)v.y, (_Float16)v.z, (_Float16)v.w};
        *(half4*)(out + i * 4) = o;
    }
}

// WT[mat][n][k] = W[mat][k][n], fp16. mats: convW 0..3, W_att = 4
__global__ __launch_bounds__(256) void k_prepw(const float* __restrict__ convW, const float* __restrict__ W_att,
                                               _Float16* __restrict__ WT) {
    int idx = blockIdx.x * 256 + threadIdx.x;   // 5*16384 total
    int mat = idx >> 14, rem = idx & 16383;
    int n = rem >> 7, k = rem & 127;
    const float* src = (mat < 4) ? (convW + mat * 16384) : W_att;
    WT[idx] = (_Float16)src[k * 128 + n];
}

// ---------------- GEMM: hWs[M,128] = (A[M,128] @ W) * dinv[row], fp16 in/out, fp32 acc ----------------
// A-frag (16x16x32): lane holds A[m=l&15][k=(l>>4)*8+j]; B-frag: B[k][n=l&15] read from WT[n][k].
// C/D: col = l&15, row = (l>>4)*4 + reg
__global__ __launch_bounds__(256) void k_gemm_f16(const _Float16* __restrict__ A, const _Float16* __restrict__ WT,
                                                  const float* __restrict__ dinv,
                                                  _Float16* __restrict__ C, int M) {
    __shared__ float Cs[64][132];
    int tid = threadIdx.x;
    int wave = tid >> 6, lane = tid & 63;
    int quad = lane >> 4, l15 = lane & 15;
    int m0 = blockIdx.x * 64;
    int ko = quad * 8;

    floatx4 acc[4][2];
#pragma unroll
    for (int rt = 0; rt < 4; ++rt)
#pragma unroll
        for (int ct = 0; ct < 2; ++ct) acc[rt][ct] = (floatx4){0.f, 0.f, 0.f, 0.f};

#pragma unroll
    for (int kk = 0; kk < 4; ++kk) {
        half8 a[4], b[2];
#pragma unroll
        for (int rt = 0; rt < 4; ++rt) {
            int row = m0 + rt * 16 + l15;
            if (row > M - 1) row = M - 1;
            a[rt] = *(const half8*)(A + row * 128 + kk * 32 + ko);
        }
#pragma unroll
        for (int ct = 0; ct < 2; ++ct) {
            int n = wave * 32 + ct * 16 + l15;
            b[ct] = *(const half8*)(WT + n * 128 + kk * 32 + ko);
        }
#pragma unroll
        for (int rt = 0; rt < 4; ++rt)
#pragma unroll
            for (int ct = 0; ct < 2; ++ct)
                acc[rt][ct] = __builtin_amdgcn_mfma_f32_16x16x32_f16(a[rt], b[ct], acc[rt][ct], 0, 0, 0);
    }

    // epilogue: LDS bounce -> coalesced fp16 rows, scaled by dinv[row]
#pragma unroll
    for (int rt = 0; rt < 4; ++rt)
#pragma unroll
        for (int ct = 0; ct < 2; ++ct)
#pragma unroll
            for (int r = 0; r < 4; ++r)
                Cs[rt * 16 + quad * 4 + r][wave * 32 + ct * 16 + l15] = acc[rt][ct][r];
    __syncthreads();
    int row = tid >> 2, seg = tid & 3;
    int gm = m0 + row;
    if (gm < M) {
        float sc = dinv[gm];
#pragma unroll
        for (int j = 0; j < 4; ++j) {
            float4 f0 = *(const float4*)&Cs[row][seg * 32 + j * 8];
            float4 f1 = *(const float4*)&Cs[row][seg * 32 + j * 8 + 4];
            half8 o = {(_Float16)(f0.x * sc), (_Float16)(f0.y * sc), (_Float16)(f0.z * sc), (_Float16)(f0.w * sc),
                       (_Float16)(f1.x * sc), (_Float16)(f1.y * sc), (_Float16)(f1.z * sc), (_Float16)(f1.w * sc)};
            *(half8*)(C + gm * 128 + seg * 32 + j * 8) = o;
        }
    }
}

// ---------------- edge aggregation: wave per node, unroll-8 gather (8 outstanding), no dinv in loop ----------------
// hWs rows are pre-scaled by dinv[src]; result = (sum + hWs[n]) * dinv[n] + bias, relu, fp16 out.
__global__ __launch_bounds__(256) void k_aggregate(const _Float16* __restrict__ hWs, const int* __restrict__ offsets,
                                                   const int* __restrict__ esrc, const float* __restrict__ dinv,
                                                   const float* __restrict__ bias, _Float16* __restrict__ outh) {
    __shared__ float bsh[128];
    int tid = threadIdx.x;
    if (tid < 128) bsh[tid] = bias[tid];
    __syncthreads();
    int lane = tid & 63, wave = tid >> 6;
    int n = blockIdx.x * 4 + wave;
    int beg = offsets[n], end = offsets[n + 1];
    int c2 = lane * 2;
    float ax0 = 0.f, ay0 = 0.f, ax1 = 0.f, ay1 = 0.f;
    int e = beg;
    for (; e + 8 <= end; e += 8) {
        int s0 = esrc[e + 0], s1 = esrc[e + 1], s2 = esrc[e + 2], s3 = esrc[e + 3];
        int s4 = esrc[e + 4], s5 = esrc[e + 5], s6 = esrc[e + 6], s7 = esrc[e + 7];
        half2v v0 = *(const half2v*)(hWs + (size_t)s0 * 128 + c2);
        half2v v1 = *(const half2v*)(hWs + (size_t)s1 * 128 + c2);
        half2v v2 = *(const half2v*)(hWs + (size_t)s2 * 128 + c2);
        half2v v3 = *(const half2v*)(hWs + (size_t)s3 * 128 + c2);
        half2v v4 = *(const half2v*)(hWs + (size_t)s4 * 128 + c2);
        half2v v5 = *(const half2v*)(hWs + (size_t)s5 * 128 + c2);
        half2v v6 = *(const half2v*)(hWs + (size_t)s6 * 128 + c2);
        half2v v7 = *(const half2v*)(hWs + (size_t)s7 * 128 + c2);
        ax0 += (float)v0.x + (float)v1.x + (float)v2.x + (float)v3.x;
        ay0 += (float)v0.y + (float)v1.y + (float)v2.y + (float)v3.y;
        ax1 += (float)v4.x + (float)v5.x + (float)v6.x + (float)v7.x;
        ay1 += (float)v4.y + (float)v5.y + (float)v6.y + (float)v7.y;
    }
    for (; e < end; ++e) {
        int s = esrc[e];
        half2v v = *(const half2v*)(hWs + (size_t)s * 128 + c2);
        ax0 += (float)v.x; ay0 += (float)v.y;
    }
    float dn = dinv[n];
    half2v sv = *(const half2v*)(hWs + (size_t)n * 128 + c2);
    float r0 = (ax0 + ax1 + (float)sv.x) * dn + bsh[c2];
    float r1 = (ay0 + ay1 + (float)sv.y) * dn + bsh[c2 + 1];
    half2v o = {(_Float16)fmaxf(r0, 0.f), (_Float16)fmaxf(r1, 0.f)};
    *(half2v*)(outh + (size_t)n * 128 + c2) = o;
}

// ---------------- attention scores via MFMA: scores[m] = a . tanh(H[m] @ W_att), m = n*4+l ----------------
__global__ __launch_bounds__(256) void k_attn(const _Float16* __restrict__ h0, const _Float16* __restrict__ h1,
                                              const _Float16* __restrict__ h2, const _Float16* __restrict__ h3,
                                              const _Float16* __restrict__ WT, const float* __restrict__ a_att,
                                              float* __restrict__ scores) {
    int tid = threadIdx.x;
    int wave = tid >> 6, lane = tid & 63;
    int quad = lane >> 4, l15 = lane & 15;
    int mw = blockIdx.x * 64 + wave * 16;     // 16 rows per wave; M=200000 exact
    int m = mw + l15;
    int layer = m & 3, node = m >> 2;
    const _Float16* hb = (layer & 2) ? ((layer & 1) ? h3 : h2) : ((layer & 1) ? h1 : h0);
    const _Float16* Ap = hb + node * 128 + quad * 8;
    half8 a[4];
#pragma unroll
    for (int kk = 0; kk < 4; ++kk) a[kk] = *(const half8*)(Ap + kk * 32);

    float p[4] = {0.f, 0.f, 0.f, 0.f};
#pragma unroll
    for (int ct = 0; ct < 8; ++ct) {
        int n = ct * 16 + l15;
        const _Float16* Bp = WT + n * 128 + quad * 8;
        floatx4 acc = (floatx4){0.f, 0.f, 0.f, 0.f};
#pragma unroll
        for (int kk = 0; kk < 4; ++kk)
            acc = __builtin_amdgcn_mfma_f32_16x16x32_f16(a[kk], *(const half8*)(Bp + kk * 32), acc, 0, 0, 0);
        float av = a_att[n];
#pragma unroll
        for (int r = 0; r < 4; ++r) p[r] += av * fast_tanh(acc[r]);
    }
#pragma unroll
    for (int r = 0; r < 4; ++r) {
        p[r] += __shfl_xor(p[r], 1); p[r] += __shfl_xor(p[r], 2);
        p[r] += __shfl_xor(p[r], 4); p[r] += __shfl_xor(p[r], 8);
    }
    if (l15 == 0) {
#pragma unroll
        for (int r = 0; r < 4; ++r) scores[mw + quad * 4 + r] = p[r];
    }
}

// ---------------- softmax over layers + fuse + output projection (fp32 math, fp16 h reads) ----------------
__global__ __launch_bounds__(256) void k_fuse_out(const _Float16* __restrict__ h0, const _Float16* __restrict__ h1,
                                                  const _Float16* __restrict__ h2, const _Float16* __restrict__ h3,
                                                  const float* __restrict__ scores, const float* __restrict__ Wout,
                                                  const float* __restrict__ bout, float* __restrict__ out) {
    __shared__ float WoT[NCLASS * 132];   // transposed W_out: WoT[j*132 + c]
    __shared__ float bsh[NCLASS];
    __shared__ float fused[4][128];
    int tid = threadIdx.x;
    for (int idx = tid; idx < 128 * NCLASS; idx += 256) {
        int c = idx / NCLASS, j = idx % NCLASS;
        WoT[j * 132 + c] = Wout[idx];
    }
    if (tid < NCLASS) bsh[tid] = bout[tid];
    __syncthreads();

    int lane = tid & 63, wave = tid >> 6;
    int n = blockIdx.x * 4 + wave;
    float s0 = scores[n * 4 + 0], s1 = scores[n * 4 + 1];
    float s2 = scores[n * 4 + 2], s3 = scores[n * 4 + 3];
    float mx = fmaxf(fmaxf(s0, s1), fmaxf(s2, s3));
    float e0 = expf(s0 - mx), e1 = expf(s1 - mx), e2 = expf(s2 - mx), e3 = expf(s3 - mx);
    float inv = 1.0f / (e0 + e1 + e2 + e3);
    e0 *= inv; e1 *= inv; e2 *= inv; e3 *= inv;

    int c2 = lane * 2;
    half2v v0 = *(const half2v*)(h0 + n * 128 + c2);
    half2v v1 = *(const half2v*)(h1 + n * 128 + c2);
    half2v v2 = *(const half2v*)(h2 + n * 128 + c2);
    half2v v3 = *(const half2v*)(h3 + n * 128 + c2);
    float2 f;
    f.x = e0 * (float)v0.x + e1 * (float)v1.x + e2 * (float)v2.x + e3 * (float)v3.x;
    f.y = e0 * (float)v0.y + e1 * (float)v1.y + e2 * (float)v2.y + e3 * (float)v3.y;
    *(float2*)&fused[wave][c2] = f;   // same-wave LDS RAW: compiler inserts lgkmcnt wait

    if (lane < NCLASS) {
        float acc = bsh[lane];
#pragma unroll
        for (int k = 0; k < 128; k += 4) {
            float4 f4 = *(const float4*)&fused[wave][k];
            float4 w4 = *(const float4*)&WoT[lane * 132 + k];
            acc += f4.x * w4.x + f4.y * w4.y + f4.z * w4.z + f4.w * w4.w;
        }
        out[n * NCLASS + lane] = acc;
    }
}

extern "C" void kernel_launch(void* const* d_in, const int* in_sizes, int n_in,
                              void* d_out, int out_size, void* d_ws, size_t ws_size,
                              hipStream_t stream) {
    const float* x     = (const float*)d_in[0];
    const int*   ei    = (const int*)d_in[1];
    const float* convW = (const float*)d_in[2];
    const float* convb = (const float*)d_in[3];
    const float* W_att = (const float*)d_in[4];
    const float* a_att = (const float*)d_in[5];
    const float* W_out = (const float*)d_in[6];
    const float* b_out = (const float*)d_in[7];
    float* out = (float*)d_out;

    char* ws = (char*)d_ws;
    size_t off = 0;
    auto take = [&](size_t nbytes) { char* p = ws + off; off += (nbytes + 255) & ~(size_t)255; return p; };
    float*     dinv    = (float*)take(NNODES * 4);
    int*       cnt     = (int*)take(NNODES * 4);
    int*       cursor  = (int*)take(NNODES * 4);
    int*       offsets = (int*)take((NNODES + 1) * 4);
    int*       esrc    = (int*)take(NEDGES * 4);
    float*     scores  = (float*)take(NNODES * 4 * 4);
    _Float16*  xh      = (_Float16*)take((size_t)NNODES * 128 * 2);
    _Float16*  WT      = (_Float16*)take((size_t)5 * 128 * 128 * 2);
    _Float16*  hWs     = (_Float16*)take((size_t)NNODES * 128 * 2);
    _Float16*  hh[4];
    for (int l = 0; l < 4; ++l) hh[l] = (_Float16*)take((size_t)NNODES * 128 * 2);

    const int* src = ei;
    const int* dst = ei + NEDGES;

    hipMemsetAsync(cnt, 0, NNODES * 4, stream);
    k_count<<<NEDGES / 256, 256, 0, stream>>>(dst, cnt);
    k_dinv<<<(NNODES + 255) / 256, 256, 0, stream>>>(cnt, dinv);
    k_scan<<<1, 1024, 0, stream>>>(cnt, offsets);
    hipMemsetAsync(cursor, 0, NNODES * 4, stream);
    k_fill<<<NEDGES / 256, 256, 0, stream>>>(src, dst, offsets, cursor, esrc);

    k_f2h<<<(NNODES * 128 / 4 + 255) / 256, 256, 0, stream>>>(x, xh, NNODES * 128 / 4);
    k_prepw<<<(5 * 16384) / 256, 256, 0, stream>>>(convW, W_att, WT);

    const _Float16* hprev = xh;
    for (int l = 0; l < 4; ++l) {
        k_gemm_f16<<<(NNODES + 63) / 64, 256, 0, stream>>>(hprev, WT + l * 16384, dinv, hWs, NNODES);
        k_aggregate<<<NNODES / 4, 256, 0, stream>>>(hWs, offsets, esrc, dinv, convb + l * 128, hh[l]);
        hprev = hh[l];
    }
    k_attn<<<(NNODES * 4) / 64, 256, 0, stream>>>(hh[0], hh[1], hh[2], hh[3], WT + 4 * 16384, a_att, scores);
    k_fuse_out<<<NNODES / 4, 256, 0, stream>>>(hh[0], hh[1], hh[2], hh[3], scores, W_out, b_out, out);
}

// Round 4
// 510.583 us; speedup vs baseline: 1.6281x; 1.1378x over previous
//
#include <hip/hip_runtime.h>

#define NNODES 50000
#define NEDGES 800000
#define NCLASS 40
#define NBLK_SCAN 196   // ceil(50000/256)

typedef _Float16 half8  __attribute__((ext_vector_type(8)));
typedef _Float16 half4  __attribute__((ext_vector_type(4)));
typedef _Float16 half2v __attribute__((ext_vector_type(2)));
typedef float    floatx4 __attribute__((ext_vector_type(4)));

__device__ __forceinline__ float fast_tanh(float x) {
    return 1.0f - 2.0f / (__expf(2.0f * x) + 1.0f);
}

// ---------------- CSR build ----------------
__global__ __launch_bounds__(256) void k_count(const int* __restrict__ dst, int* __restrict__ cnt) {
    int e = blockIdx.x * 256 + threadIdx.x;
    atomicAdd(&cnt[dst[e]], 1);
}

// block sums of cnt (196 blocks x 256)
__global__ __launch_bounds__(256) void k_bsum(const int* __restrict__ cnt, int* __restrict__ bsum) {
    int t = threadIdx.x, b = blockIdx.x;
    int i = b * 256 + t;
    int c = (i < NNODES) ? cnt[i] : 0;
    int v = c;
    v += __shfl_xor(v, 1);  v += __shfl_xor(v, 2);  v += __shfl_xor(v, 4);
    v += __shfl_xor(v, 8);  v += __shfl_xor(v, 16); v += __shfl_xor(v, 32);
    __shared__ int ws[4];
    if ((t & 63) == 0) ws[t >> 6] = v;
    __syncthreads();
    if (t == 0) bsum[b] = ws[0] + ws[1] + ws[2] + ws[3];
}

// per-block exclusive scan + block offset (sum of bsum[0..b-1]) + dinv, all in one
__global__ __launch_bounds__(256) void k_offsets(const int* __restrict__ cnt, const int* __restrict__ bsum,
                                                 int* __restrict__ offsets, float* __restrict__ dinv) {
    int t = threadIdx.x, b = blockIdx.x;
    int i = b * 256 + t;
    int c = (i < NNODES) ? cnt[i] : 0;

    // block offset: reduce bsum[t] over t < b
    int pv = (t < b) ? bsum[t] : 0;   // b <= 195 < 256
    int rv = pv;
    rv += __shfl_xor(rv, 1);  rv += __shfl_xor(rv, 2);  rv += __shfl_xor(rv, 4);
    rv += __shfl_xor(rv, 8);  rv += __shfl_xor(rv, 16); rv += __shfl_xor(rv, 32);
    __shared__ int wsum[4];
    __shared__ int part[256];
    if ((t & 63) == 0) wsum[t >> 6] = rv;
    part[t] = c;
    __syncthreads();
    int boff = wsum[0] + wsum[1] + wsum[2] + wsum[3];

    // Hillis-Steele inclusive scan of c over 256
#pragma unroll
    for (int d = 1; d < 256; d <<= 1) {
        int v = (t >= d) ? part[t - d] : 0;
        __syncthreads();
        part[t] += v;
        __syncthreads();
    }
    if (i < NNODES) {
        offsets[i] = boff + part[t] - c;   // exclusive
        dinv[i] = rsqrtf((float)c + 1.0f);
    }
    if (b == 0 && t == 0) offsets[NNODES] = NEDGES;
}

__global__ __launch_bounds__(256) void k_fill(const int* __restrict__ src, const int* __restrict__ dst,
                                              const int* __restrict__ offsets, int* __restrict__ cursor,
                                              int* __restrict__ esrc) {
    int e = blockIdx.x * 256 + threadIdx.x;
    int d = dst[e];
    int pos = atomicAdd(&cursor[d], 1);
    esrc[offsets[d] + pos] = src[e];
}

// ---------------- fp32 -> fp16 conversions ----------------
__global__ __launch_bounds__(256) void k_f2h(const float* __restrict__ in, _Float16* __restrict__ out, int n4) {
    int i = blockIdx.x * 256 + threadIdx.x;
    if (i < n4) {
        float4 v = *(const float4*)(in + i * 4);
        half4 o = {(_Float16)v.x, (_Float16)v.y, (_Float16)v.z, (_Float16)v.w};
        *(half4*)(out + i * 4) = o;
    }
}

// WT[mat][n][k] = W[mat][k][n], fp16. mats: convW 0..3, W_att = 4
__global__ __launch_bounds__(256) void k_prepw(const float* __restrict__ convW, const float* __restrict__ W_att,
                                               _Float16* __restrict__ WT) {
    int idx = blockIdx.x * 256 + threadIdx.x;   // 5*16384 total
    int mat = idx >> 14, rem = idx & 16383;
    int n = rem >> 7, k = rem & 127;
    const float* src = (mat < 4) ? (convW + mat * 16384) : W_att;
    WT[idx] = (_Float16)src[k * 128 + n];
}

// ---------------- GEMM: hWs[M,128] = (A[M,128] @ W) * dinv[row], fp16 in/out, fp32 acc ----------------
__global__ __launch_bounds__(256) void k_gemm_f16(const _Float16* __restrict__ A, const _Float16* __restrict__ WT,
                                                  const float* __restrict__ dinv,
                                                  _Float16* __restrict__ C, int M) {
    __shared__ float Cs[64][132];
    int tid = threadIdx.x;
    int wave = tid >> 6, lane = tid & 63;
    int quad = lane >> 4, l15 = lane & 15;
    int m0 = blockIdx.x * 64;
    int ko = quad * 8;

    floatx4 acc[4][2];
#pragma unroll
    for (int rt = 0; rt < 4; ++rt)
#pragma unroll
        for (int ct = 0; ct < 2; ++ct) acc[rt][ct] = (floatx4){0.f, 0.f, 0.f, 0.f};

#pragma unroll
    for (int kk = 0; kk < 4; ++kk) {
        half8 a[4], b[2];
#pragma unroll
        for (int rt = 0; rt < 4; ++rt) {
            int row = m0 + rt * 16 + l15;
            if (row > M - 1) row = M - 1;
            a[rt] = *(const half8*)(A + row * 128 + kk * 32 + ko);
        }
#pragma unroll
        for (int ct = 0; ct < 2; ++ct) {
            int n = wave * 32 + ct * 16 + l15;
            b[ct] = *(const half8*)(WT + n * 128 + kk * 32 + ko);
        }
#pragma unroll
        for (int rt = 0; rt < 4; ++rt)
#pragma unroll
            for (int ct = 0; ct < 2; ++ct)
                acc[rt][ct] = __builtin_amdgcn_mfma_f32_16x16x32_f16(a[rt], b[ct], acc[rt][ct], 0, 0, 0);
    }

#pragma unroll
    for (int rt = 0; rt < 4; ++rt)
#pragma unroll
        for (int ct = 0; ct < 2; ++ct)
#pragma unroll
            for (int r = 0; r < 4; ++r)
                Cs[rt * 16 + quad * 4 + r][wave * 32 + ct * 16 + l15] = acc[rt][ct][r];
    __syncthreads();
    int row = tid >> 2, seg = tid & 3;
    int gm = m0 + row;
    if (gm < M) {
        float sc = dinv[gm];
#pragma unroll
        for (int j = 0; j < 4; ++j) {
            float4 f0 = *(const float4*)&Cs[row][seg * 32 + j * 8];
            float4 f1 = *(const float4*)&Cs[row][seg * 32 + j * 8 + 4];
            half8 o = {(_Float16)(f0.x * sc), (_Float16)(f0.y * sc), (_Float16)(f0.z * sc), (_Float16)(f0.w * sc),
                       (_Float16)(f1.x * sc), (_Float16)(f1.y * sc), (_Float16)(f1.z * sc), (_Float16)(f1.w * sc)};
            *(half8*)(C + gm * 128 + seg * 32 + j * 8) = o;
        }
    }
}

// ---------------- edge aggregation: half-wave per edge-row (half4/lane), unroll 8 -> 16 rows in flight/wave ----
__global__ __launch_bounds__(256) void k_aggregate(const _Float16* __restrict__ hWs, const int* __restrict__ offsets,
                                                   const int* __restrict__ esrc, const float* __restrict__ dinv,
                                                   const float* __restrict__ bias, _Float16* __restrict__ outh) {
    __shared__ float bsh[128];
    int tid = threadIdx.x;
    if (tid < 128) bsh[tid] = bias[tid];
    __syncthreads();
    int lane = tid & 63, wave = tid >> 6;
    int n = blockIdx.x * 4 + wave;
    int half = lane >> 5, w32 = lane & 31;
    int c4 = w32 * 4;
    int beg = offsets[n], end = offsets[n + 1];
    float ax = 0.f, ay = 0.f, az = 0.f, aw = 0.f;
    int e = beg + half;
    for (; e + 14 < end; e += 16) {       // 8 gathers per half-wave (edges e, e+2, ..., e+14)
        int s0 = esrc[e +  0], s1 = esrc[e +  2], s2 = esrc[e +  4], s3 = esrc[e +  6];
        int s4 = esrc[e +  8], s5 = esrc[e + 10], s6 = esrc[e + 12], s7 = esrc[e + 14];
        half4 v0 = *(const half4*)(hWs + (size_t)s0 * 128 + c4);
        half4 v1 = *(const half4*)(hWs + (size_t)s1 * 128 + c4);
        half4 v2 = *(const half4*)(hWs + (size_t)s2 * 128 + c4);
        half4 v3 = *(const half4*)(hWs + (size_t)s3 * 128 + c4);
        half4 v4 = *(const half4*)(hWs + (size_t)s4 * 128 + c4);
        half4 v5 = *(const half4*)(hWs + (size_t)s5 * 128 + c4);
        half4 v6 = *(const half4*)(hWs + (size_t)s6 * 128 + c4);
        half4 v7 = *(const half4*)(hWs + (size_t)s7 * 128 + c4);
        ax += (float)v0.x + (float)v1.x + (float)v2.x + (float)v3.x
            + (float)v4.x + (float)v5.x + (float)v6.x + (float)v7.x;
        ay += (float)v0.y + (float)v1.y + (float)v2.y + (float)v3.y
            + (float)v4.y + (float)v5.y + (float)v6.y + (float)v7.y;
        az += (float)v0.z + (float)v1.z + (float)v2.z + (float)v3.z
            + (float)v4.z + (float)v5.z + (float)v6.z + (float)v7.z;
        aw += (float)v0.w + (float)v1.w + (float)v2.w + (float)v3.w
            + (float)v4.w + (float)v5.w + (float)v6.w + (float)v7.w;
    }
    for (; e < end; e += 2) {
        int s = esrc[e];
        half4 v = *(const half4*)(hWs + (size_t)s * 128 + c4);
        ax += (float)v.x; ay += (float)v.y; az += (float)v.z; aw += (float)v.w;
    }
    // combine the two halves (col c lives in lane c/4 and lane 32+c/4)
    ax += __shfl_xor(ax, 32); ay += __shfl_xor(ay, 32);
    az += __shfl_xor(az, 32); aw += __shfl_xor(aw, 32);
    if (half == 0) {
        float dn = dinv[n];
        half4 sv = *(const half4*)(hWs + (size_t)n * 128 + c4);
        float r0 = (ax + (float)sv.x) * dn + bsh[c4 + 0];
        float r1 = (ay + (float)sv.y) * dn + bsh[c4 + 1];
        float r2 = (az + (float)sv.z) * dn + bsh[c4 + 2];
        float r3 = (aw + (float)sv.w) * dn + bsh[c4 + 3];
        half4 o = {(_Float16)fmaxf(r0, 0.f), (_Float16)fmaxf(r1, 0.f),
                   (_Float16)fmaxf(r2, 0.f), (_Float16)fmaxf(r3, 0.f)};
        *(half4*)(outh + (size_t)n * 128 + c4) = o;
    }
}

// ---------------- attention scores via MFMA ----------------
__global__ __launch_bounds__(256) void k_attn(const _Float16* __restrict__ h0, const _Float16* __restrict__ h1,
                                              const _Float16* __restrict__ h2, const _Float16* __restrict__ h3,
                                              const _Float16* __restrict__ WT, const float* __restrict__ a_att,
                                              float* __restrict__ scores) {
    int tid = threadIdx.x;
    int wave = tid >> 6, lane = tid & 63;
    int quad = lane >> 4, l15 = lane & 15;
    int mw = blockIdx.x * 64 + wave * 16;
    int m = mw + l15;
    int layer = m & 3, node = m >> 2;
    const _Float16* hb = (layer & 2) ? ((layer & 1) ? h3 : h2) : ((layer & 1) ? h1 : h0);
    const _Float16* Ap = hb + node * 128 + quad * 8;
    half8 a[4];
#pragma unroll
    for (int kk = 0; kk < 4; ++kk) a[kk] = *(const half8*)(Ap + kk * 32);

    float p[4] = {0.f, 0.f, 0.f, 0.f};
#pragma unroll
    for (int ct = 0; ct < 8; ++ct) {
        int n = ct * 16 + l15;
        const _Float16* Bp = WT + n * 128 + quad * 8;
        floatx4 acc = (floatx4){0.f, 0.f, 0.f, 0.f};
#pragma unroll
        for (int kk = 0; kk < 4; ++kk)
            acc = __builtin_amdgcn_mfma_f32_16x16x32_f16(a[kk], *(const half8*)(Bp + kk * 32), acc, 0, 0, 0);
        float av = a_att[n];
#pragma unroll
        for (int r = 0; r < 4; ++r) p[r] += av * fast_tanh(acc[r]);
    }
#pragma unroll
    for (int r = 0; r < 4; ++r) {
        p[r] += __shfl_xor(p[r], 1); p[r] += __shfl_xor(p[r], 2);
        p[r] += __shfl_xor(p[r], 4); p[r] += __shfl_xor(p[r], 8);
    }
    if (l15 == 0) {
#pragma unroll
        for (int r = 0; r < 4; ++r) scores[mw + quad * 4 + r] = p[r];
    }
}

// ---------------- softmax + fuse + output projection ----------------
__global__ __launch_bounds__(256) void k_fuse_out(const _Float16* __restrict__ h0, const _Float16* __restrict__ h1,
                                                  const _Float16* __restrict__ h2, const _Float16* __restrict__ h3,
                                                  const float* __restrict__ scores, const float* __restrict__ Wout,
                                                  const float* __restrict__ bout, float* __restrict__ out) {
    __shared__ float WoT[NCLASS * 132];
    __shared__ float bsh[NCLASS];
    __shared__ float fused[4][128];
    int tid = threadIdx.x;
    for (int idx = tid; idx < 128 * NCLASS; idx += 256) {
        int c = idx / NCLASS, j = idx % NCLASS;
        WoT[j * 132 + c] = Wout[idx];
    }
    if (tid < NCLASS) bsh[tid] = bout[tid];
    __syncthreads();

    int lane = tid & 63, wave = tid >> 6;
    int n = blockIdx.x * 4 + wave;
    float s0 = scores[n * 4 + 0], s1 = scores[n * 4 + 1];
    float s2 = scores[n * 4 + 2], s3 = scores[n * 4 + 3];
    float mx = fmaxf(fmaxf(s0, s1), fmaxf(s2, s3));
    float e0 = expf(s0 - mx), e1 = expf(s1 - mx), e2 = expf(s2 - mx), e3 = expf(s3 - mx);
    float inv = 1.0f / (e0 + e1 + e2 + e3);
    e0 *= inv; e1 *= inv; e2 *= inv; e3 *= inv;

    int c2 = lane * 2;
    half2v v0 = *(const half2v*)(h0 + n * 128 + c2);
    half2v v1 = *(const half2v*)(h1 + n * 128 + c2);
    half2v v2 = *(const half2v*)(h2 + n * 128 + c2);
    half2v v3 = *(const half2v*)(h3 + n * 128 + c2);
    float2 f;
    f.x = e0 * (float)v0.x + e1 * (float)v1.x + e2 * (float)v2.x + e3 * (float)v3.x;
    f.y = e0 * (float)v0.y + e1 * (float)v1.y + e2 * (float)v2.y + e3 * (float)v3.y;
    *(float2*)&fused[wave][c2] = f;

    if (lane < NCLASS) {
        float acc = bsh[lane];
#pragma unroll
        for (int k = 0; k < 128; k += 4) {
            float4 f4 = *(const float4*)&fused[wave][k];
            float4 w4 = *(const float4*)&WoT[lane * 132 + k];
            acc += f4.x * w4.x + f4.y * w4.y + f4.z * w4.z + f4.w * w4.w;
        }
        out[n * NCLASS + lane] = acc;
    }
}

extern "C" void kernel_launch(void* const* d_in, const int* in_sizes, int n_in,
                              void* d_out, int out_size, void* d_ws, size_t ws_size,
                              hipStream_t stream) {
    const float* x     = (const float*)d_in[0];
    const int*   ei    = (const int*)d_in[1];
    const float* convW = (const float*)d_in[2];
    const float* convb = (const float*)d_in[3];
    const float* W_att = (const float*)d_in[4];
    const float* a_att = (const float*)d_in[5];
    const float* W_out = (const float*)d_in[6];
    const float* b_out = (const float*)d_in[7];
    float* out = (float*)d_out;

    char* ws = (char*)d_ws;
    size_t off = 0;
    auto take = [&](size_t nbytes) { char* p = ws + off; off += (nbytes + 255) & ~(size_t)255; return p; };
    float*     dinv    = (float*)take(NNODES * 4);
    int*       cnt     = (int*)take(NNODES * 4);     // cnt and cursor adjacent: one memset covers both
    int*       cursor  = (int*)take(NNODES * 4);
    int*       offsets = (int*)take((NNODES + 1) * 4);
    int*       bsum    = (int*)take(256 * 4);
    int*       esrc    = (int*)take(NEDGES * 4);
    float*     scores  = (float*)take(NNODES * 4 * 4);
    _Float16*  xh      = (_Float16*)take((size_t)NNODES * 128 * 2);
    _Float16*  WT      = (_Float16*)take((size_t)5 * 128 * 128 * 2);
    _Float16*  hWs     = (_Float16*)take((size_t)NNODES * 128 * 2);
    _Float16*  hh[4];
    for (int l = 0; l < 4; ++l) hh[l] = (_Float16*)take((size_t)NNODES * 128 * 2);

    const int* src = ei;
    const int* dst = ei + NEDGES;

    size_t cntpad = (((size_t)NNODES * 4 + 255) & ~(size_t)255);
    hipMemsetAsync(cnt, 0, cntpad + NNODES * 4, stream);   // zeroes cnt + cursor
    k_count<<<NEDGES / 256, 256, 0, stream>>>(dst, cnt);
    k_bsum<<<NBLK_SCAN, 256, 0, stream>>>(cnt, bsum);
    k_offsets<<<NBLK_SCAN, 256, 0, stream>>>(cnt, bsum, offsets, dinv);
    k_fill<<<NEDGES / 256, 256, 0, stream>>>(src, dst, offsets, cursor, esrc);

    k_f2h<<<(NNODES * 128 / 4 + 255) / 256, 256, 0, stream>>>(x, xh, NNODES * 128 / 4);
    k_prepw<<<(5 * 16384) / 256, 256, 0, stream>>>(convW, W_att, WT);

    const _Float16* hprev = xh;
    for (int l = 0; l < 4; ++l) {
        k_gemm_f16<<<(NNODES + 63) / 64, 256, 0, stream>>>(hprev, WT + l * 16384, dinv, hWs, NNODES);
        k_aggregate<<<NNODES / 4, 256, 0, stream>>>(hWs, offsets, esrc, dinv, convb + l * 128, hh[l]);
        hprev = hh[l];
    }
    k_attn<<<(NNODES * 4) / 64, 256, 0, stream>>>(hh[0], hh[1], hh[2], hh[3], WT + 4 * 16384, a_att, scores);
    k_fuse_out<<<NNODES / 4, 256, 0, stream>>>(hh[0], hh[1], hh[2], hh[3], scores, W_out, b_out, out);
}

// Round 5
// 489.808 us; speedup vs baseline: 1.6971x; 1.0424x over previous
//
#include <hip/hip_runtime.h>

#define NNODES 50000
#define NEDGES 800000
#define NCLASS 40
#define NBLK_SCAN 196   // ceil(50000/256)

typedef _Float16 half8  __attribute__((ext_vector_type(8)));
typedef _Float16 half4  __attribute__((ext_vector_type(4)));
typedef _Float16 half2v __attribute__((ext_vector_type(2)));
typedef float    floatx4 __attribute__((ext_vector_type(4)));

__device__ __forceinline__ float fast_tanh(float x) {
    return 1.0f - 2.0f / (__expf(2.0f * x) + 1.0f);
}

// ---------------- CSR build ----------------
__global__ __launch_bounds__(256) void k_count(const int* __restrict__ dst, int* __restrict__ cnt) {
    int e = blockIdx.x * 256 + threadIdx.x;
    atomicAdd(&cnt[dst[e]], 1);
}

__global__ __launch_bounds__(256) void k_bsum(const int* __restrict__ cnt, int* __restrict__ bsum) {
    int t = threadIdx.x, b = blockIdx.x;
    int i = b * 256 + t;
    int c = (i < NNODES) ? cnt[i] : 0;
    int v = c;
    v += __shfl_xor(v, 1);  v += __shfl_xor(v, 2);  v += __shfl_xor(v, 4);
    v += __shfl_xor(v, 8);  v += __shfl_xor(v, 16); v += __shfl_xor(v, 32);
    __shared__ int ws[4];
    if ((t & 63) == 0) ws[t >> 6] = v;
    __syncthreads();
    if (t == 0) bsum[b] = ws[0] + ws[1] + ws[2] + ws[3];
}

__global__ __launch_bounds__(256) void k_offsets(const int* __restrict__ cnt, const int* __restrict__ bsum,
                                                 int* __restrict__ offsets, float* __restrict__ dinv) {
    int t = threadIdx.x, b = blockIdx.x;
    int i = b * 256 + t;
    int c = (i < NNODES) ? cnt[i] : 0;
    int pv = (t < b) ? bsum[t] : 0;   // b <= 195 < 256
    int rv = pv;
    rv += __shfl_xor(rv, 1);  rv += __shfl_xor(rv, 2);  rv += __shfl_xor(rv, 4);
    rv += __shfl_xor(rv, 8);  rv += __shfl_xor(rv, 16); rv += __shfl_xor(rv, 32);
    __shared__ int wsum[4];
    __shared__ int part[256];
    if ((t & 63) == 0) wsum[t >> 6] = rv;
    part[t] = c;
    __syncthreads();
    int boff = wsum[0] + wsum[1] + wsum[2] + wsum[3];
#pragma unroll
    for (int d = 1; d < 256; d <<= 1) {
        int v = (t >= d) ? part[t - d] : 0;
        __syncthreads();
        part[t] += v;
        __syncthreads();
    }
    if (i < NNODES) {
        offsets[i] = boff + part[t] - c;
        dinv[i] = rsqrtf((float)c + 1.0f);
    }
    if (b == 0 && t == 0) offsets[NNODES] = NEDGES;
}

__global__ __launch_bounds__(256) void k_fill(const int* __restrict__ src, const int* __restrict__ dst,
                                              const int* __restrict__ offsets, int* __restrict__ cursor,
                                              int* __restrict__ esrc) {
    int e = blockIdx.x * 256 + threadIdx.x;
    int d = dst[e];
    int pos = atomicAdd(&cursor[d], 1);
    esrc[offsets[d] + pos] = src[e];
}

// ---------------- fp32 -> fp16 conversions ----------------
__global__ __launch_bounds__(256) void k_f2h(const float* __restrict__ in, _Float16* __restrict__ out, int n4) {
    int i = blockIdx.x * 256 + threadIdx.x;
    if (i < n4) {
        float4 v = *(const float4*)(in + i * 4);
        half4 o = {(_Float16)v.x, (_Float16)v.y, (_Float16)v.z, (_Float16)v.w};
        *(half4*)(out + i * 4) = o;
    }
}

// WT[mat][n][k] = W[mat][k][n], fp16. mats: convW 0..3, W_att = 4
__global__ __launch_bounds__(256) void k_prepw(const float* __restrict__ convW, const float* __restrict__ W_att,
                                               _Float16* __restrict__ WT) {
    int idx = blockIdx.x * 256 + threadIdx.x;   // 5*16384 total
    int mat = idx >> 14, rem = idx & 16383;
    int n = rem >> 7, k = rem & 127;
    const float* src = (mat < 4) ? (convW + mat * 16384) : W_att;
    WT[idx] = (_Float16)src[k * 128 + n];
}

// ---------------- GEMM: hWs[M,128] = (A[M,128] @ W) * dinv[row], fp16 in/out, fp32 acc ----------------
__global__ __launch_bounds__(256) void k_gemm_f16(const _Float16* __restrict__ A, const _Float16* __restrict__ WT,
                                                  const float* __restrict__ dinv,
                                                  _Float16* __restrict__ C, int M) {
    __shared__ float Cs[64][132];
    int tid = threadIdx.x;
    int wave = tid >> 6, lane = tid & 63;
    int quad = lane >> 4, l15 = lane & 15;
    int m0 = blockIdx.x * 64;
    int ko = quad * 8;

    floatx4 acc[4][2];
#pragma unroll
    for (int rt = 0; rt < 4; ++rt)
#pragma unroll
        for (int ct = 0; ct < 2; ++ct) acc[rt][ct] = (floatx4){0.f, 0.f, 0.f, 0.f};

#pragma unroll
    for (int kk = 0; kk < 4; ++kk) {
        half8 a[4], b[2];
#pragma unroll
        for (int rt = 0; rt < 4; ++rt) {
            int row = m0 + rt * 16 + l15;
            if (row > M - 1) row = M - 1;
            a[rt] = *(const half8*)(A + row * 128 + kk * 32 + ko);
        }
#pragma unroll
        for (int ct = 0; ct < 2; ++ct) {
            int n = wave * 32 + ct * 16 + l15;
            b[ct] = *(const half8*)(WT + n * 128 + kk * 32 + ko);
        }
#pragma unroll
        for (int rt = 0; rt < 4; ++rt)
#pragma unroll
            for (int ct = 0; ct < 2; ++ct)
                acc[rt][ct] = __builtin_amdgcn_mfma_f32_16x16x32_f16(a[rt], b[ct], acc[rt][ct], 0, 0, 0);
    }

#pragma unroll
    for (int rt = 0; rt < 4; ++rt)
#pragma unroll
        for (int ct = 0; ct < 2; ++ct)
#pragma unroll
            for (int r = 0; r < 4; ++r)
                Cs[rt * 16 + quad * 4 + r][wave * 32 + ct * 16 + l15] = acc[rt][ct][r];
    __syncthreads();
    int row = tid >> 2, seg = tid & 3;
    int gm = m0 + row;
    if (gm < M) {
        float sc = dinv[gm];
#pragma unroll
        for (int j = 0; j < 4; ++j) {
            float4 f0 = *(const float4*)&Cs[row][seg * 32 + j * 8];
            float4 f1 = *(const float4*)&Cs[row][seg * 32 + j * 8 + 4];
            half8 o = {(_Float16)(f0.x * sc), (_Float16)(f0.y * sc), (_Float16)(f0.z * sc), (_Float16)(f0.w * sc),
                       (_Float16)(f1.x * sc), (_Float16)(f1.y * sc), (_Float16)(f1.z * sc), (_Float16)(f1.w * sc)};
            *(half8*)(C + gm * 128 + seg * 32 + j * 8) = o;
        }
    }
}

// ---------------- edge aggregation: quarter-wave rows (half8/lane), 2 nodes/wave, 2 parities, unroll 8 ------
__global__ __launch_bounds__(256) void k_aggregate(const _Float16* __restrict__ hWs, const int* __restrict__ offsets,
                                                   const int* __restrict__ esrc, const float* __restrict__ dinv,
                                                   const float* __restrict__ bias, _Float16* __restrict__ outh) {
    __shared__ float bsh[128];
    int tid = threadIdx.x;
    if (tid < 128) bsh[tid] = bias[tid];
    __syncthreads();
    int lane = tid & 63, wave = tid >> 6;
    int half = lane >> 5;          // which node within the wave
    int q = (lane >> 4) & 1;       // edge parity within the node
    int l16 = lane & 15;
    int c8 = l16 * 8;
    int n = blockIdx.x * 8 + wave * 2 + half;
    int beg = offsets[n], end = offsets[n + 1];
    float a0 = 0.f, a1 = 0.f, a2 = 0.f, a3 = 0.f, a4 = 0.f, a5 = 0.f, a6 = 0.f, a7 = 0.f;
    int e = beg + q;
    for (; e + 14 < end; e += 16) {     // 8 edges per parity (e, e+2, ..., e+14)
        int s0 = esrc[e +  0], s1 = esrc[e +  2], s2 = esrc[e +  4], s3 = esrc[e +  6];
        int s4 = esrc[e +  8], s5 = esrc[e + 10], s6 = esrc[e + 12], s7 = esrc[e + 14];
        half8 v0 = *(const half8*)(hWs + (size_t)s0 * 128 + c8);
        half8 v1 = *(const half8*)(hWs + (size_t)s1 * 128 + c8);
        half8 v2 = *(const half8*)(hWs + (size_t)s2 * 128 + c8);
        half8 v3 = *(const half8*)(hWs + (size_t)s3 * 128 + c8);
        half8 v4 = *(const half8*)(hWs + (size_t)s4 * 128 + c8);
        half8 v5 = *(const half8*)(hWs + (size_t)s5 * 128 + c8);
        half8 v6 = *(const half8*)(hWs + (size_t)s6 * 128 + c8);
        half8 v7 = *(const half8*)(hWs + (size_t)s7 * 128 + c8);
        a0 += (float)v0[0]+(float)v1[0]+(float)v2[0]+(float)v3[0]+(float)v4[0]+(float)v5[0]+(float)v6[0]+(float)v7[0];
        a1 += (float)v0[1]+(float)v1[1]+(float)v2[1]+(float)v3[1]+(float)v4[1]+(float)v5[1]+(float)v6[1]+(float)v7[1];
        a2 += (float)v0[2]+(float)v1[2]+(float)v2[2]+(float)v3[2]+(float)v4[2]+(float)v5[2]+(float)v6[2]+(float)v7[2];
        a3 += (float)v0[3]+(float)v1[3]+(float)v2[3]+(float)v3[3]+(float)v4[3]+(float)v5[3]+(float)v6[3]+(float)v7[3];
        a4 += (float)v0[4]+(float)v1[4]+(float)v2[4]+(float)v3[4]+(float)v4[4]+(float)v5[4]+(float)v6[4]+(float)v7[4];
        a5 += (float)v0[5]+(float)v1[5]+(float)v2[5]+(float)v3[5]+(float)v4[5]+(float)v5[5]+(float)v6[5]+(float)v7[5];
        a6 += (float)v0[6]+(float)v1[6]+(float)v2[6]+(float)v3[6]+(float)v4[6]+(float)v5[6]+(float)v6[6]+(float)v7[6];
        a7 += (float)v0[7]+(float)v1[7]+(float)v2[7]+(float)v3[7]+(float)v4[7]+(float)v5[7]+(float)v6[7]+(float)v7[7];
    }
    for (; e < end; e += 2) {
        int s = esrc[e];
        half8 v = *(const half8*)(hWs + (size_t)s * 128 + c8);
        a0 += (float)v[0]; a1 += (float)v[1]; a2 += (float)v[2]; a3 += (float)v[3];
        a4 += (float)v[4]; a5 += (float)v[5]; a6 += (float)v[6]; a7 += (float)v[7];
    }
    // combine parities (lane l <-> l^16 within each 32-half)
    a0 += __shfl_xor(a0, 16); a1 += __shfl_xor(a1, 16); a2 += __shfl_xor(a2, 16); a3 += __shfl_xor(a3, 16);
    a4 += __shfl_xor(a4, 16); a5 += __shfl_xor(a5, 16); a6 += __shfl_xor(a6, 16); a7 += __shfl_xor(a7, 16);
    if (q == 0) {
        float dn = dinv[n];
        half8 sv = *(const half8*)(hWs + (size_t)n * 128 + c8);
        float4 b0 = *(const float4*)&bsh[c8];
        float4 b1 = *(const float4*)&bsh[c8 + 4];
        float r0 = (a0 + (float)sv[0]) * dn + b0.x;
        float r1 = (a1 + (float)sv[1]) * dn + b0.y;
        float r2 = (a2 + (float)sv[2]) * dn + b0.z;
        float r3 = (a3 + (float)sv[3]) * dn + b0.w;
        float r4 = (a4 + (float)sv[4]) * dn + b1.x;
        float r5 = (a5 + (float)sv[5]) * dn + b1.y;
        float r6 = (a6 + (float)sv[6]) * dn + b1.z;
        float r7 = (a7 + (float)sv[7]) * dn + b1.w;
        half8 o = {(_Float16)fmaxf(r0, 0.f), (_Float16)fmaxf(r1, 0.f),
                   (_Float16)fmaxf(r2, 0.f), (_Float16)fmaxf(r3, 0.f),
                   (_Float16)fmaxf(r4, 0.f), (_Float16)fmaxf(r5, 0.f),
                   (_Float16)fmaxf(r6, 0.f), (_Float16)fmaxf(r7, 0.f)};
        *(half8*)(outh + (size_t)n * 128 + c8) = o;
    }
}

// ---------------- attention scores, gemm-shaped: 64 rows/wave, B reused across 4 row-tiles --------------
// hbase: contiguous [4][NNODES][128] layer-major is NOT the layout; layers are separate contiguous 12.8MB
// slabs: row m (= node*4+layer) lives at hbase + layer*LSTR + node*128.
__global__ __launch_bounds__(256) void k_attn(const _Float16* __restrict__ hbase, const _Float16* __restrict__ WT,
                                              const float* __restrict__ a_att, float* __restrict__ scores) {
    const size_t LSTR = (size_t)NNODES * 128;
    int tid = threadIdx.x;
    int wave = tid >> 6, lane = tid & 63;
    int quad = lane >> 4, l15 = lane & 15;
    int mwb = blockIdx.x * 256 + wave * 64;   // 64 rows per wave
    int ko = quad * 8;

    half8 a[4][4];
#pragma unroll
    for (int rt = 0; rt < 4; ++rt) {
        int m = mwb + rt * 16 + l15;
        if (m > 4 * NNODES - 1) m = 4 * NNODES - 1;
        const _Float16* Ap = hbase + (size_t)(m & 3) * LSTR + (size_t)(m >> 2) * 128 + ko;
#pragma unroll
        for (int kk = 0; kk < 4; ++kk) a[rt][kk] = *(const half8*)(Ap + kk * 32);
    }

    float p[4][4];
#pragma unroll
    for (int rt = 0; rt < 4; ++rt)
#pragma unroll
        for (int r = 0; r < 4; ++r) p[rt][r] = 0.f;

#pragma unroll
    for (int ct = 0; ct < 8; ++ct) {
        int ncol = ct * 16 + l15;
        const _Float16* Bp = WT + ncol * 128 + ko;
        half8 b[4];
#pragma unroll
        for (int kk = 0; kk < 4; ++kk) b[kk] = *(const half8*)(Bp + kk * 32);
        floatx4 acc[4];
#pragma unroll
        for (int rt = 0; rt < 4; ++rt) acc[rt] = (floatx4){0.f, 0.f, 0.f, 0.f};
#pragma unroll
        for (int kk = 0; kk < 4; ++kk)
#pragma unroll
            for (int rt = 0; rt < 4; ++rt)
                acc[rt] = __builtin_amdgcn_mfma_f32_16x16x32_f16(a[rt][kk], b[kk], acc[rt], 0, 0, 0);
        float av = a_att[ncol];
#pragma unroll
        for (int rt = 0; rt < 4; ++rt)
#pragma unroll
            for (int r = 0; r < 4; ++r) p[rt][r] += av * fast_tanh(acc[rt][r]);
    }
#pragma unroll
    for (int rt = 0; rt < 4; ++rt)
#pragma unroll
        for (int r = 0; r < 4; ++r) {
            float v = p[rt][r];
            v += __shfl_xor(v, 1); v += __shfl_xor(v, 2);
            v += __shfl_xor(v, 4); v += __shfl_xor(v, 8);
            p[rt][r] = v;
        }
    if (l15 == 0) {
#pragma unroll
        for (int rt = 0; rt < 4; ++rt)
#pragma unroll
            for (int r = 0; r < 4; ++r) {
                int m = mwb + rt * 16 + quad * 4 + r;
                if (m < 4 * NNODES) scores[m] = p[rt][r];
            }
    }
}

// ---------------- softmax + fuse + output projection ----------------
__global__ __launch_bounds__(256) void k_fuse_out(const _Float16* __restrict__ h0, const _Float16* __restrict__ h1,
                                                  const _Float16* __restrict__ h2, const _Float16* __restrict__ h3,
                                                  const float* __restrict__ scores, const float* __restrict__ Wout,
                                                  const float* __restrict__ bout, float* __restrict__ out) {
    __shared__ float WoT[NCLASS * 132];
    __shared__ float bsh[NCLASS];
    __shared__ float fused[4][128];
    int tid = threadIdx.x;
    for (int idx = tid; idx < 128 * NCLASS; idx += 256) {
        int c = idx / NCLASS, j = idx % NCLASS;
        WoT[j * 132 + c] = Wout[idx];
    }
    if (tid < NCLASS) bsh[tid] = bout[tid];
    __syncthreads();

    int lane = tid & 63, wave = tid >> 6;
    int n = blockIdx.x * 4 + wave;
    float s0 = scores[n * 4 + 0], s1 = scores[n * 4 + 1];
    float s2 = scores[n * 4 + 2], s3 = scores[n * 4 + 3];
    float mx = fmaxf(fmaxf(s0, s1), fmaxf(s2, s3));
    float e0 = expf(s0 - mx), e1 = expf(s1 - mx), e2 = expf(s2 - mx), e3 = expf(s3 - mx);
    float inv = 1.0f / (e0 + e1 + e2 + e3);
    e0 *= inv; e1 *= inv; e2 *= inv; e3 *= inv;

    int c2 = lane * 2;
    half2v v0 = *(const half2v*)(h0 + n * 128 + c2);
    half2v v1 = *(const half2v*)(h1 + n * 128 + c2);
    half2v v2 = *(const half2v*)(h2 + n * 128 + c2);
    half2v v3 = *(const half2v*)(h3 + n * 128 + c2);
    float2 f;
    f.x = e0 * (float)v0.x + e1 * (float)v1.x + e2 * (float)v2.x + e3 * (float)v3.x;
    f.y = e0 * (float)v0.y + e1 * (float)v1.y + e2 * (float)v2.y + e3 * (float)v3.y;
    *(float2*)&fused[wave][c2] = f;

    if (lane < NCLASS) {
        float acc = bsh[lane];
#pragma unroll
        for (int k = 0; k < 128; k += 4) {
            float4 f4 = *(const float4*)&fused[wave][k];
            float4 w4 = *(const float4*)&WoT[lane * 132 + k];
            acc += f4.x * w4.x + f4.y * w4.y + f4.z * w4.z + f4.w * w4.w;
        }
        out[n * NCLASS + lane] = acc;
    }
}

extern "C" void kernel_launch(void* const* d_in, const int* in_sizes, int n_in,
                              void* d_out, int out_size, void* d_ws, size_t ws_size,
                              hipStream_t stream) {
    const float* x     = (const float*)d_in[0];
    const int*   ei    = (const int*)d_in[1];
    const float* convW = (const float*)d_in[2];
    const float* convb = (const float*)d_in[3];
    const float* W_att = (const float*)d_in[4];
    const float* a_att = (const float*)d_in[5];
    const float* W_out = (const float*)d_in[6];
    const float* b_out = (const float*)d_in[7];
    float* out = (float*)d_out;

    char* ws = (char*)d_ws;
    size_t off = 0;
    auto take = [&](size_t nbytes) { char* p = ws + off; off += (nbytes + 255) & ~(size_t)255; return p; };
    float*     dinv    = (float*)take(NNODES * 4);
    int*       cnt     = (int*)take(NNODES * 4);     // cnt and cursor adjacent: one memset covers both
    int*       cursor  = (int*)take(NNODES * 4);
    int*       offsets = (int*)take((NNODES + 1) * 4);
    int*       bsum    = (int*)take(256 * 4);
    int*       esrc    = (int*)take(NEDGES * 4);
    float*     scores  = (float*)take(NNODES * 4 * 4);
    _Float16*  xh      = (_Float16*)take((size_t)NNODES * 128 * 2);
    _Float16*  WT      = (_Float16*)take((size_t)5 * 128 * 128 * 2);
    _Float16*  hWs     = (_Float16*)take((size_t)NNODES * 128 * 2);
    _Float16*  hh[4];
    for (int l = 0; l < 4; ++l) hh[l] = (_Float16*)take((size_t)NNODES * 128 * 2);
    // NOTE: each hh slab is 12,800,000 B (multiple of 256) -> hh[0..3] are contiguous; k_attn relies on it.

    const int* src = ei;
    const int* dst = ei + NEDGES;

    size_t cntpad = (((size_t)NNODES * 4 + 255) & ~(size_t)255);
    hipMemsetAsync(cnt, 0, cntpad + NNODES * 4, stream);   // zeroes cnt + cursor
    k_count<<<NEDGES / 256, 256, 0, stream>>>(dst, cnt);
    k_bsum<<<NBLK_SCAN, 256, 0, stream>>>(cnt, bsum);
    k_offsets<<<NBLK_SCAN, 256, 0, stream>>>(cnt, bsum, offsets, dinv);
    k_fill<<<NEDGES / 256, 256, 0, stream>>>(src, dst, offsets, cursor, esrc);

    k_f2h<<<(NNODES * 128 / 4 + 255) / 256, 256, 0, stream>>>(x, xh, NNODES * 128 / 4);
    k_prepw<<<(5 * 16384) / 256, 256, 0, stream>>>(convW, W_att, WT);

    const _Float16* hprev = xh;
    for (int l = 0; l < 4; ++l) {
        k_gemm_f16<<<(NNODES + 63) / 64, 256, 0, stream>>>(hprev, WT + l * 16384, dinv, hWs, NNODES);
        k_aggregate<<<NNODES / 8, 256, 0, stream>>>(hWs, offsets, esrc, dinv, convb + l * 128, hh[l]);
        hprev = hh[l];
    }
    k_attn<<<(NNODES * 4 + 255) / 256, 256, 0, stream>>>(hh[0], WT + 4 * 16384, a_att, scores);
    k_fuse_out<<<NNODES / 4, 256, 0, stream>>>(hh[0], hh[1], hh[2], hh[3], scores, W_out, b_out, out);
}

// Round 6
// 399.750 us; speedup vs baseline: 2.0795x; 1.2253x over previous
//
#include <hip/hip_runtime.h>

#define NNODES 50000
#define NEDGES 800000
#define NCLASS 40
#define NBLK_SCAN 196   // ceil(50000/256)
#define CNTB  3125      // NEDGES/256
#define F2HB  6250      // NNODES*128/4/256
#define PREPB 320       // 5*16384/256
#define GEMMB 782       // ceil(NNODES/64)

typedef _Float16 half8  __attribute__((ext_vector_type(8)));
typedef _Float16 half4  __attribute__((ext_vector_type(4)));
typedef _Float16 half2v __attribute__((ext_vector_type(2)));
typedef float    floatx4 __attribute__((ext_vector_type(4)));

__device__ __forceinline__ float fast_tanh(float x) {
    return 1.0f - 2.0f / (__expf(2.0f * x) + 1.0f);
}

// ---------------- fused pre-pass: count+rank | f2h | prepw ----------------
__global__ __launch_bounds__(256) void k_pre(const int* __restrict__ dst, int* __restrict__ cnt,
                                             int* __restrict__ rank,
                                             const float* __restrict__ x, _Float16* __restrict__ xh,
                                             const float* __restrict__ convW, const float* __restrict__ W_att,
                                             _Float16* __restrict__ WT) {
    int bid = blockIdx.x, tid = threadIdx.x;
    if (bid < CNTB) {
        int e = bid * 256 + tid;
        rank[e] = atomicAdd(&cnt[dst[e]], 1);
    } else if (bid < CNTB + F2HB) {
        int i = (bid - CNTB) * 256 + tid;
        float4 v = *(const float4*)(x + (size_t)i * 4);
        half4 o = {(_Float16)v.x, (_Float16)v.y, (_Float16)v.z, (_Float16)v.w};
        *(half4*)(xh + (size_t)i * 4) = o;
    } else {
        int idx = (bid - CNTB - F2HB) * 256 + tid;   // < 5*16384
        int mat = idx >> 14, rem = idx & 16383;
        int n = rem >> 7, k = rem & 127;
        const float* src = (mat < 4) ? (convW + mat * 16384) : W_att;
        WT[idx] = (_Float16)src[k * 128 + n];
    }
}

__global__ __launch_bounds__(256) void k_bsum(const int* __restrict__ cnt, int* __restrict__ bsum) {
    int t = threadIdx.x, b = blockIdx.x;
    int i = b * 256 + t;
    int c = (i < NNODES) ? cnt[i] : 0;
    int v = c;
    v += __shfl_xor(v, 1);  v += __shfl_xor(v, 2);  v += __shfl_xor(v, 4);
    v += __shfl_xor(v, 8);  v += __shfl_xor(v, 16); v += __shfl_xor(v, 32);
    __shared__ int ws[4];
    if ((t & 63) == 0) ws[t >> 6] = v;
    __syncthreads();
    if (t == 0) bsum[b] = ws[0] + ws[1] + ws[2] + ws[3];
}

__global__ __launch_bounds__(256) void k_offsets(const int* __restrict__ cnt, const int* __restrict__ bsum,
                                                 int* __restrict__ offsets, float* __restrict__ dinv) {
    int t = threadIdx.x, b = blockIdx.x;
    int i = b * 256 + t;
    int c = (i < NNODES) ? cnt[i] : 0;
    int pv = (t < b) ? bsum[t] : 0;   // b <= 195 < 256
    int rv = pv;
    rv += __shfl_xor(rv, 1);  rv += __shfl_xor(rv, 2);  rv += __shfl_xor(rv, 4);
    rv += __shfl_xor(rv, 8);  rv += __shfl_xor(rv, 16); rv += __shfl_xor(rv, 32);
    __shared__ int wsum[4];
    __shared__ int part[256];
    if ((t & 63) == 0) wsum[t >> 6] = rv;
    part[t] = c;
    __syncthreads();
    int boff = wsum[0] + wsum[1] + wsum[2] + wsum[3];
#pragma unroll
    for (int d = 1; d < 256; d <<= 1) {
        int v = (t >= d) ? part[t - d] : 0;
        __syncthreads();
        part[t] += v;
        __syncthreads();
    }
    if (i < NNODES) {
        offsets[i] = boff + part[t] - c;
        dinv[i] = rsqrtf((float)c + 1.0f);
    }
    if (b == 0 && t == 0) offsets[NNODES] = NEDGES;
}

// ---------------- shared GEMM body: C[64,128] tile = (A @ W) * dinv ----------------
__device__ __forceinline__ void gemm_body(const _Float16* __restrict__ A, const _Float16* __restrict__ WT,
                                          const float* __restrict__ dinv, _Float16* __restrict__ C,
                                          int m0, float (*Cs)[132]) {
    int tid = threadIdx.x;
    int wave = tid >> 6, lane = tid & 63;
    int quad = lane >> 4, l15 = lane & 15;
    int ko = quad * 8;

    floatx4 acc[4][2];
#pragma unroll
    for (int rt = 0; rt < 4; ++rt)
#pragma unroll
        for (int ct = 0; ct < 2; ++ct) acc[rt][ct] = (floatx4){0.f, 0.f, 0.f, 0.f};

#pragma unroll
    for (int kk = 0; kk < 4; ++kk) {
        half8 a[4], b[2];
#pragma unroll
        for (int rt = 0; rt < 4; ++rt) {
            int row = m0 + rt * 16 + l15;
            if (row > NNODES - 1) row = NNODES - 1;
            a[rt] = *(const half8*)(A + (size_t)row * 128 + kk * 32 + ko);
        }
#pragma unroll
        for (int ct = 0; ct < 2; ++ct) {
            int n = wave * 32 + ct * 16 + l15;
            b[ct] = *(const half8*)(WT + n * 128 + kk * 32 + ko);
        }
#pragma unroll
        for (int rt = 0; rt < 4; ++rt)
#pragma unroll
            for (int ct = 0; ct < 2; ++ct)
                acc[rt][ct] = __builtin_amdgcn_mfma_f32_16x16x32_f16(a[rt], b[ct], acc[rt][ct], 0, 0, 0);
    }

#pragma unroll
    for (int rt = 0; rt < 4; ++rt)
#pragma unroll
        for (int ct = 0; ct < 2; ++ct)
#pragma unroll
            for (int r = 0; r < 4; ++r)
                Cs[rt * 16 + quad * 4 + r][wave * 32 + ct * 16 + l15] = acc[rt][ct][r];
    __syncthreads();
    int row = tid >> 2, seg = tid & 3;
    int gm = m0 + row;
    if (gm < NNODES) {
        float sc = dinv[gm];
#pragma unroll
        for (int j = 0; j < 4; ++j) {
            float4 f0 = *(const float4*)&Cs[row][seg * 32 + j * 8];
            float4 f1 = *(const float4*)&Cs[row][seg * 32 + j * 8 + 4];
            half8 o = {(_Float16)(f0.x * sc), (_Float16)(f0.y * sc), (_Float16)(f0.z * sc), (_Float16)(f0.w * sc),
                       (_Float16)(f1.x * sc), (_Float16)(f1.y * sc), (_Float16)(f1.z * sc), (_Float16)(f1.w * sc)};
            *(half8*)(C + (size_t)gm * 128 + seg * 32 + j * 8) = o;
        }
    }
}

__global__ __launch_bounds__(256) void k_gemm_f16(const _Float16* __restrict__ A, const _Float16* __restrict__ WT,
                                                  const float* __restrict__ dinv, _Float16* __restrict__ C) {
    __shared__ float Cs[64][132];
    gemm_body(A, WT, dinv, C, blockIdx.x * 64, Cs);
}

// ---------------- fused: CSR fill (no atomic) | layer-0 GEMM ----------------
__global__ __launch_bounds__(256) void k_fillgemm(const int* __restrict__ src, const int* __restrict__ dst,
                                                  const int* __restrict__ offsets, const int* __restrict__ rank,
                                                  int* __restrict__ esrc,
                                                  const _Float16* __restrict__ A, const _Float16* __restrict__ WT,
                                                  const float* __restrict__ dinv, _Float16* __restrict__ C) {
    __shared__ float Cs[64][132];
    int bid = blockIdx.x;
    if (bid < GEMMB) {
        gemm_body(A, WT, dinv, C, bid * 64, Cs);
    } else {
        int e = (bid - GEMMB) * 256 + threadIdx.x;
        int d = dst[e];
        esrc[offsets[d] + rank[e]] = src[e];
    }
}

// ---------------- edge aggregation: quarter-wave rows, fully predicated 8-wide gather windows ----------
__global__ __launch_bounds__(256) void k_aggregate(const _Float16* __restrict__ hWs, const int* __restrict__ offsets,
                                                   const int* __restrict__ esrc, const float* __restrict__ dinv,
                                                   const float* __restrict__ bias, _Float16* __restrict__ outh) {
    __shared__ float bsh[128];
    int tid = threadIdx.x;
    if (tid < 128) bsh[tid] = bias[tid];
    __syncthreads();
    int lane = tid & 63, wave = tid >> 6;
    int half = lane >> 5;          // which node within the wave
    int q = (lane >> 4) & 1;       // edge parity within the node
    int l16 = lane & 15;
    int c8 = l16 * 8;
    int n = blockIdx.x * 8 + wave * 2 + half;
    int beg = offsets[n], end = offsets[n + 1];
    float a0 = 0.f, a1 = 0.f, a2 = 0.f, a3 = 0.f, a4 = 0.f, a5 = 0.f, a6 = 0.f, a7 = 0.f;
    for (int e = beg + q; e < end; e += 16) {
        int  idx[8];
        float msk[8];
#pragma unroll
        for (int i = 0; i < 8; ++i) {
            int ei = e + 2 * i;
            int t = esrc[ei];            // esrc padded by 64 ints: speculative load is in-bounds
            bool ok = ei < end;
            idx[i] = ok ? t : n;         // dummy gathers hit the hot self row
            msk[i] = ok ? 1.f : 0.f;
        }
        half8 v[8];
#pragma unroll
        for (int i = 0; i < 8; ++i) v[i] = *(const half8*)(hWs + (size_t)idx[i] * 128 + c8);
#pragma unroll
        for (int i = 0; i < 8; ++i) {
            a0 += msk[i] * (float)v[i][0]; a1 += msk[i] * (float)v[i][1];
            a2 += msk[i] * (float)v[i][2]; a3 += msk[i] * (float)v[i][3];
            a4 += msk[i] * (float)v[i][4]; a5 += msk[i] * (float)v[i][5];
            a6 += msk[i] * (float)v[i][6]; a7 += msk[i] * (float)v[i][7];
        }
    }
    a0 += __shfl_xor(a0, 16); a1 += __shfl_xor(a1, 16); a2 += __shfl_xor(a2, 16); a3 += __shfl_xor(a3, 16);
    a4 += __shfl_xor(a4, 16); a5 += __shfl_xor(a5, 16); a6 += __shfl_xor(a6, 16); a7 += __shfl_xor(a7, 16);
    if (q == 0) {
        float dn = dinv[n];
        half8 sv = *(const half8*)(hWs + (size_t)n * 128 + c8);
        float4 b0 = *(const float4*)&bsh[c8];
        float4 b1 = *(const float4*)&bsh[c8 + 4];
        float r0 = (a0 + (float)sv[0]) * dn + b0.x;
        float r1 = (a1 + (float)sv[1]) * dn + b0.y;
        float r2 = (a2 + (float)sv[2]) * dn + b0.z;
        float r3 = (a3 + (float)sv[3]) * dn + b0.w;
        float r4 = (a4 + (float)sv[4]) * dn + b1.x;
        float r5 = (a5 + (float)sv[5]) * dn + b1.y;
        float r6 = (a6 + (float)sv[6]) * dn + b1.z;
        float r7 = (a7 + (float)sv[7]) * dn + b1.w;
        half8 o = {(_Float16)fmaxf(r0, 0.f), (_Float16)fmaxf(r1, 0.f),
                   (_Float16)fmaxf(r2, 0.f), (_Float16)fmaxf(r3, 0.f),
                   (_Float16)fmaxf(r4, 0.f), (_Float16)fmaxf(r5, 0.f),
                   (_Float16)fmaxf(r6, 0.f), (_Float16)fmaxf(r7, 0.f)};
        *(half8*)(outh + (size_t)n * 128 + c8) = o;
    }
}

// ---------------- attention scores, gemm-shaped: 64 rows/wave, B reused across 4 row-tiles --------------
__global__ __launch_bounds__(256) void k_attn(const _Float16* __restrict__ hbase, const _Float16* __restrict__ WT,
                                              const float* __restrict__ a_att, float* __restrict__ scores) {
    const size_t LSTR = (size_t)NNODES * 128;
    int tid = threadIdx.x;
    int wave = tid >> 6, lane = tid & 63;
    int quad = lane >> 4, l15 = lane & 15;
    int mwb = blockIdx.x * 256 + wave * 64;
    int ko = quad * 8;

    half8 a[4][4];
#pragma unroll
    for (int rt = 0; rt < 4; ++rt) {
        int m = mwb + rt * 16 + l15;
        if (m > 4 * NNODES - 1) m = 4 * NNODES - 1;
        const _Float16* Ap = hbase + (size_t)(m & 3) * LSTR + (size_t)(m >> 2) * 128 + ko;
#pragma unroll
        for (int kk = 0; kk < 4; ++kk) a[rt][kk] = *(const half8*)(Ap + kk * 32);
    }

    float p[4][4];
#pragma unroll
    for (int rt = 0; rt < 4; ++rt)
#pragma unroll
        for (int r = 0; r < 4; ++r) p[rt][r] = 0.f;

#pragma unroll
    for (int ct = 0; ct < 8; ++ct) {
        int ncol = ct * 16 + l15;
        const _Float16* Bp = WT + ncol * 128 + ko;
        half8 b[4];
#pragma unroll
        for (int kk = 0; kk < 4; ++kk) b[kk] = *(const half8*)(Bp + kk * 32);
        floatx4 acc[4];
#pragma unroll
        for (int rt = 0; rt < 4; ++rt) acc[rt] = (floatx4){0.f, 0.f, 0.f, 0.f};
#pragma unroll
        for (int kk = 0; kk < 4; ++kk)
#pragma unroll
            for (int rt = 0; rt < 4; ++rt)
                acc[rt] = __builtin_amdgcn_mfma_f32_16x16x32_f16(a[rt][kk], b[kk], acc[rt], 0, 0, 0);
        float av = a_att[ncol];
#pragma unroll
        for (int rt = 0; rt < 4; ++rt)
#pragma unroll
            for (int r = 0; r < 4; ++r) p[rt][r] += av * fast_tanh(acc[rt][r]);
    }
#pragma unroll
    for (int rt = 0; rt < 4; ++rt)
#pragma unroll
        for (int r = 0; r < 4; ++r) {
            float v = p[rt][r];
            v += __shfl_xor(v, 1); v += __shfl_xor(v, 2);
            v += __shfl_xor(v, 4); v += __shfl_xor(v, 8);
            p[rt][r] = v;
        }
    if (l15 == 0) {
#pragma unroll
        for (int rt = 0; rt < 4; ++rt)
#pragma unroll
            for (int r = 0; r < 4; ++r) {
                int m = mwb + rt * 16 + quad * 4 + r;
                if (m < 4 * NNODES) scores[m] = p[rt][r];
            }
    }
}

// ---------------- softmax + fuse + output projection ----------------
__global__ __launch_bounds__(256) void k_fuse_out(const _Float16* __restrict__ h0, const _Float16* __restrict__ h1,
                                                  const _Float16* __restrict__ h2, const _Float16* __restrict__ h3,
                                                  const float* __restrict__ scores, const float* __restrict__ Wout,
                                                  const float* __restrict__ bout, float* __restrict__ out) {
    __shared__ float WoT[NCLASS * 132];
    __shared__ float bsh[NCLASS];
    __shared__ float fused[4][128];
    int tid = threadIdx.x;
    for (int idx = tid; idx < 128 * NCLASS; idx += 256) {
        int c = idx / NCLASS, j = idx % NCLASS;
        WoT[j * 132 + c] = Wout[idx];
    }
    if (tid < NCLASS) bsh[tid] = bout[tid];
    __syncthreads();

    int lane = tid & 63, wave = tid >> 6;
    int n = blockIdx.x * 4 + wave;
    float s0 = scores[n * 4 + 0], s1 = scores[n * 4 + 1];
    float s2 = scores[n * 4 + 2], s3 = scores[n * 4 + 3];
    float mx = fmaxf(fmaxf(s0, s1), fmaxf(s2, s3));
    float e0 = expf(s0 - mx), e1 = expf(s1 - mx), e2 = expf(s2 - mx), e3 = expf(s3 - mx);
    float inv = 1.0f / (e0 + e1 + e2 + e3);
    e0 *= inv; e1 *= inv; e2 *= inv; e3 *= inv;

    int c2 = lane * 2;
    half2v v0 = *(const half2v*)(h0 + n * 128 + c2);
    half2v v1 = *(const half2v*)(h1 + n * 128 + c2);
    half2v v2 = *(const half2v*)(h2 + n * 128 + c2);
    half2v v3 = *(const half2v*)(h3 + n * 128 + c2);
    float2 f;
    f.x = e0 * (float)v0.x + e1 * (float)v1.x + e2 * (float)v2.x + e3 * (float)v3.x;
    f.y = e0 * (float)v0.y + e1 * (float)v1.y + e2 * (float)v2.y + e3 * (float)v3.y;
    *(float2*)&fused[wave][c2] = f;

    if (lane < NCLASS) {
        float acc = bsh[lane];
#pragma unroll
        for (int k = 0; k < 128; k += 4) {
            float4 f4 = *(const float4*)&fused[wave][k];
            float4 w4 = *(const float4*)&WoT[lane * 132 + k];
            acc += f4.x * w4.x + f4.y * w4.y + f4.z * w4.z + f4.w * w4.w;
        }
        out[n * NCLASS + lane] = acc;
    }
}

extern "C" void kernel_launch(void* const* d_in, const int* in_sizes, int n_in,
                              void* d_out, int out_size, void* d_ws, size_t ws_size,
                              hipStream_t stream) {
    const float* x     = (const float*)d_in[0];
    const int*   ei    = (const int*)d_in[1];
    const float* convW = (const float*)d_in[2];
    const float* convb = (const float*)d_in[3];
    const float* W_att = (const float*)d_in[4];
    const float* a_att = (const float*)d_in[5];
    const float* W_out = (const float*)d_in[6];
    const float* b_out = (const float*)d_in[7];
    float* out = (float*)d_out;

    char* ws = (char*)d_ws;
    size_t off = 0;
    auto take = [&](size_t nbytes) { char* p = ws + off; off += (nbytes + 255) & ~(size_t)255; return p; };
    float*     dinv    = (float*)take(NNODES * 4);
    int*       cnt     = (int*)take(NNODES * 4);
    int*       rank    = (int*)take(NEDGES * 4);
    int*       offsets = (int*)take((NNODES + 1) * 4);
    int*       bsum    = (int*)take(256 * 4);
    int*       esrc    = (int*)take(NEDGES * 4 + 256);   // +64 ints pad for speculative loads
    float*     scores  = (float*)take(NNODES * 4 * 4);
    _Float16*  xh      = (_Float16*)take((size_t)NNODES * 128 * 2);
    _Float16*  WT      = (_Float16*)take((size_t)5 * 128 * 128 * 2);
    _Float16*  hWs     = (_Float16*)take((size_t)NNODES * 128 * 2);
    _Float16*  hh[4];
    for (int l = 0; l < 4; ++l) hh[l] = (_Float16*)take((size_t)NNODES * 128 * 2);
    // NOTE: hh slabs are 12,800,000 B each (multiple of 256) -> contiguous; k_attn relies on it.

    const int* src = ei;
    const int* dst = ei + NEDGES;

    hipMemsetAsync(cnt, 0, NNODES * 4, stream);
    k_pre<<<CNTB + F2HB + PREPB, 256, 0, stream>>>(dst, cnt, rank, x, xh, convW, W_att, WT);
    k_bsum<<<NBLK_SCAN, 256, 0, stream>>>(cnt, bsum);
    k_offsets<<<NBLK_SCAN, 256, 0, stream>>>(cnt, bsum, offsets, dinv);
    k_fillgemm<<<GEMMB + CNTB, 256, 0, stream>>>(src, dst, offsets, rank, esrc, xh, WT, dinv, hWs);

    k_aggregate<<<NNODES / 8, 256, 0, stream>>>(hWs, offsets, esrc, dinv, convb + 0 * 128, hh[0]);
    for (int l = 1; l < 4; ++l) {
        k_gemm_f16<<<GEMMB, 256, 0, stream>>>(hh[l - 1], WT + l * 16384, dinv, hWs);
        k_aggregate<<<NNODES / 8, 256, 0, stream>>>(hWs, offsets, esrc, dinv, convb + l * 128, hh[l]);
    }
    k_attn<<<(NNODES * 4 + 255) / 256, 256, 0, stream>>>(hh[0], WT + 4 * 16384, a_att, scores);
    k_fuse_out<<<NNODES / 4, 256, 0, stream>>>(hh[0], hh[1], hh[2], hh[3], scores, W_out, b_out, out);
}

// Round 7
// 391.820 us; speedup vs baseline: 2.1216x; 1.0202x over previous
//
#include <hip/hip_runtime.h>

#define NNODES 50000
#define NEDGES 800000
#define NCLASS 40
#define NBLK_SCAN 196   // ceil(50000/256)
#define CNTB  3125      // NEDGES/256
#define F2HB  6250      // NNODES*128/4/256
#define PREPB 320       // 5*16384/256
#define WOUTB 24        // 48*128/256
#define GEMMB 782       // ceil(NNODES/64)
#define AFOB  782       // ceil(NNODES/64)

typedef _Float16 half8  __attribute__((ext_vector_type(8)));
typedef _Float16 half4  __attribute__((ext_vector_type(4)));
typedef _Float16 half2v __attribute__((ext_vector_type(2)));
typedef float    floatx4 __attribute__((ext_vector_type(4)));

__device__ __forceinline__ float fast_tanh(float x) {
    return 1.0f - 2.0f / (__expf(2.0f * x) + 1.0f);
}

// ---------------- fused pre-pass: count+rank | f2h | prepw | prep WoutT ----------------
__global__ __launch_bounds__(256) void k_pre(const int* __restrict__ dst, int* __restrict__ cnt,
                                             int* __restrict__ rank,
                                             const float* __restrict__ x, _Float16* __restrict__ xh,
                                             const float* __restrict__ convW, const float* __restrict__ W_att,
                                             _Float16* __restrict__ WT,
                                             const float* __restrict__ Wout, _Float16* __restrict__ WoutT) {
    int bid = blockIdx.x, tid = threadIdx.x;
    if (bid < CNTB) {
        int e = bid * 256 + tid;
        rank[e] = atomicAdd(&cnt[dst[e]], 1);
    } else if (bid < CNTB + F2HB) {
        int i = (bid - CNTB) * 256 + tid;
        float4 v = *(const float4*)(x + (size_t)i * 4);
        half4 o = {(_Float16)v.x, (_Float16)v.y, (_Float16)v.z, (_Float16)v.w};
        *(half4*)(xh + (size_t)i * 4) = o;
    } else if (bid < CNTB + F2HB + PREPB) {
        int idx = (bid - CNTB - F2HB) * 256 + tid;   // < 5*16384
        int mat = idx >> 14, rem = idx & 16383;
        int n = rem >> 7, k = rem & 127;
        const float* src = (mat < 4) ? (convW + mat * 16384) : W_att;
        WT[idx] = (_Float16)src[k * 128 + n];
    } else {
        int idx = (bid - CNTB - F2HB - PREPB) * 256 + tid;   // < 48*128
        int j = idx >> 7, c = idx & 127;
        WoutT[idx] = (j < NCLASS) ? (_Float16)Wout[c * NCLASS + j] : (_Float16)0.f;
    }
}

__global__ __launch_bounds__(256) void k_bsum(const int* __restrict__ cnt, int* __restrict__ bsum) {
    int t = threadIdx.x, b = blockIdx.x;
    int i = b * 256 + t;
    int c = (i < NNODES) ? cnt[i] : 0;
    int v = c;
    v += __shfl_xor(v, 1);  v += __shfl_xor(v, 2);  v += __shfl_xor(v, 4);
    v += __shfl_xor(v, 8);  v += __shfl_xor(v, 16); v += __shfl_xor(v, 32);
    __shared__ int ws[4];
    if ((t & 63) == 0) ws[t >> 6] = v;
    __syncthreads();
    if (t == 0) bsum[b] = ws[0] + ws[1] + ws[2] + ws[3];
}

__global__ __launch_bounds__(256) void k_offsets(const int* __restrict__ cnt, const int* __restrict__ bsum,
                                                 int* __restrict__ offsets, float* __restrict__ dinv) {
    int t = threadIdx.x, b = blockIdx.x;
    int i = b * 256 + t;
    int c = (i < NNODES) ? cnt[i] : 0;
    int pv = (t < b) ? bsum[t] : 0;   // b <= 195 < 256
    int rv = pv;
    rv += __shfl_xor(rv, 1);  rv += __shfl_xor(rv, 2);  rv += __shfl_xor(rv, 4);
    rv += __shfl_xor(rv, 8);  rv += __shfl_xor(rv, 16); rv += __shfl_xor(rv, 32);
    __shared__ int wsum[4];
    __shared__ int part[256];
    if ((t & 63) == 0) wsum[t >> 6] = rv;
    part[t] = c;
    __syncthreads();
    int boff = wsum[0] + wsum[1] + wsum[2] + wsum[3];
#pragma unroll
    for (int d = 1; d < 256; d <<= 1) {
        int v = (t >= d) ? part[t - d] : 0;
        __syncthreads();
        part[t] += v;
        __syncthreads();
    }
    if (i < NNODES) {
        offsets[i] = boff + part[t] - c;
        dinv[i] = rsqrtf((float)c + 1.0f);
    }
    if (b == 0 && t == 0) offsets[NNODES] = NEDGES;
}

// ---------------- shared GEMM body: C[64,128] tile = (A @ W) * dinv ----------------
__device__ __forceinline__ void gemm_body(const _Float16* __restrict__ A, const _Float16* __restrict__ WT,
                                          const float* __restrict__ dinv, _Float16* __restrict__ C,
                                          int m0, float (*Cs)[132]) {
    int tid = threadIdx.x;
    int wave = tid >> 6, lane = tid & 63;
    int quad = lane >> 4, l15 = lane & 15;
    int ko = quad * 8;

    floatx4 acc[4][2];
#pragma unroll
    for (int rt = 0; rt < 4; ++rt)
#pragma unroll
        for (int ct = 0; ct < 2; ++ct) acc[rt][ct] = (floatx4){0.f, 0.f, 0.f, 0.f};

#pragma unroll
    for (int kk = 0; kk < 4; ++kk) {
        half8 a[4], b[2];
#pragma unroll
        for (int rt = 0; rt < 4; ++rt) {
            int row = m0 + rt * 16 + l15;
            if (row > NNODES - 1) row = NNODES - 1;
            a[rt] = *(const half8*)(A + (size_t)row * 128 + kk * 32 + ko);
        }
#pragma unroll
        for (int ct = 0; ct < 2; ++ct) {
            int n = wave * 32 + ct * 16 + l15;
            b[ct] = *(const half8*)(WT + n * 128 + kk * 32 + ko);
        }
#pragma unroll
        for (int rt = 0; rt < 4; ++rt)
#pragma unroll
            for (int ct = 0; ct < 2; ++ct)
                acc[rt][ct] = __builtin_amdgcn_mfma_f32_16x16x32_f16(a[rt], b[ct], acc[rt][ct], 0, 0, 0);
    }

#pragma unroll
    for (int rt = 0; rt < 4; ++rt)
#pragma unroll
        for (int ct = 0; ct < 2; ++ct)
#pragma unroll
            for (int r = 0; r < 4; ++r)
                Cs[rt * 16 + quad * 4 + r][wave * 32 + ct * 16 + l15] = acc[rt][ct][r];
    __syncthreads();
    int row = tid >> 2, seg = tid & 3;
    int gm = m0 + row;
    if (gm < NNODES) {
        float sc = dinv[gm];
#pragma unroll
        for (int j = 0; j < 4; ++j) {
            float4 f0 = *(const float4*)&Cs[row][seg * 32 + j * 8];
            float4 f1 = *(const float4*)&Cs[row][seg * 32 + j * 8 + 4];
            half8 o = {(_Float16)(f0.x * sc), (_Float16)(f0.y * sc), (_Float16)(f0.z * sc), (_Float16)(f0.w * sc),
                       (_Float16)(f1.x * sc), (_Float16)(f1.y * sc), (_Float16)(f1.z * sc), (_Float16)(f1.w * sc)};
            *(half8*)(C + (size_t)gm * 128 + seg * 32 + j * 8) = o;
        }
    }
}

__global__ __launch_bounds__(256) void k_gemm_f16(const _Float16* __restrict__ A, const _Float16* __restrict__ WT,
                                                  const float* __restrict__ dinv, _Float16* __restrict__ C) {
    __shared__ float Cs[64][132];
    gemm_body(A, WT, dinv, C, blockIdx.x * 64, Cs);
}

// ---------------- fused: CSR fill (no atomic) | layer-0 GEMM ----------------
__global__ __launch_bounds__(256) void k_fillgemm(const int* __restrict__ src, const int* __restrict__ dst,
                                                  const int* __restrict__ offsets, const int* __restrict__ rank,
                                                  int* __restrict__ esrc,
                                                  const _Float16* __restrict__ A, const _Float16* __restrict__ WT,
                                                  const float* __restrict__ dinv, _Float16* __restrict__ C) {
    __shared__ float Cs[64][132];
    int bid = blockIdx.x;
    if (bid < GEMMB) {
        gemm_body(A, WT, dinv, C, bid * 64, Cs);
    } else {
        int e = (bid - GEMMB) * 256 + threadIdx.x;
        int d = dst[e];
        esrc[offsets[d] + rank[e]] = src[e];
    }
}

// ---------------- edge aggregation: quarter-wave rows, fully predicated 8-wide gather windows ----------
__global__ __launch_bounds__(256) void k_aggregate(const _Float16* __restrict__ hWs, const int* __restrict__ offsets,
                                                   const int* __restrict__ esrc, const float* __restrict__ dinv,
                                                   const float* __restrict__ bias, _Float16* __restrict__ outh) {
    __shared__ float bsh[128];
    int tid = threadIdx.x;
    if (tid < 128) bsh[tid] = bias[tid];
    __syncthreads();
    int lane = tid & 63, wave = tid >> 6;
    int half = lane >> 5;
    int q = (lane >> 4) & 1;
    int l16 = lane & 15;
    int c8 = l16 * 8;
    int n = blockIdx.x * 8 + wave * 2 + half;
    int beg = offsets[n], end = offsets[n + 1];
    float a0 = 0.f, a1 = 0.f, a2 = 0.f, a3 = 0.f, a4 = 0.f, a5 = 0.f, a6 = 0.f, a7 = 0.f;
    for (int e = beg + q; e < end; e += 16) {
        int  idx[8];
        float msk[8];
#pragma unroll
        for (int i = 0; i < 8; ++i) {
            int ei = e + 2 * i;
            int t = esrc[ei];            // esrc padded: speculative load in-bounds
            bool ok = ei < end;
            idx[i] = ok ? t : n;
            msk[i] = ok ? 1.f : 0.f;
        }
        half8 v[8];
#pragma unroll
        for (int i = 0; i < 8; ++i) v[i] = *(const half8*)(hWs + (size_t)idx[i] * 128 + c8);
#pragma unroll
        for (int i = 0; i < 8; ++i) {
            a0 += msk[i] * (float)v[i][0]; a1 += msk[i] * (float)v[i][1];
            a2 += msk[i] * (float)v[i][2]; a3 += msk[i] * (float)v[i][3];
            a4 += msk[i] * (float)v[i][4]; a5 += msk[i] * (float)v[i][5];
            a6 += msk[i] * (float)v[i][6]; a7 += msk[i] * (float)v[i][7];
        }
    }
    a0 += __shfl_xor(a0, 16); a1 += __shfl_xor(a1, 16); a2 += __shfl_xor(a2, 16); a3 += __shfl_xor(a3, 16);
    a4 += __shfl_xor(a4, 16); a5 += __shfl_xor(a5, 16); a6 += __shfl_xor(a6, 16); a7 += __shfl_xor(a7, 16);
    if (q == 0) {
        float dn = dinv[n];
        half8 sv = *(const half8*)(hWs + (size_t)n * 128 + c8);
        float4 b0 = *(const float4*)&bsh[c8];
        float4 b1 = *(const float4*)&bsh[c8 + 4];
        float r0 = (a0 + (float)sv[0]) * dn + b0.x;
        float r1 = (a1 + (float)sv[1]) * dn + b0.y;
        float r2 = (a2 + (float)sv[2]) * dn + b0.z;
        float r3 = (a3 + (float)sv[3]) * dn + b0.w;
        float r4 = (a4 + (float)sv[4]) * dn + b1.x;
        float r5 = (a5 + (float)sv[5]) * dn + b1.y;
        float r6 = (a6 + (float)sv[6]) * dn + b1.z;
        float r7 = (a7 + (float)sv[7]) * dn + b1.w;
        half8 o = {(_Float16)fmaxf(r0, 0.f), (_Float16)fmaxf(r1, 0.f),
                   (_Float16)fmaxf(r2, 0.f), (_Float16)fmaxf(r3, 0.f),
                   (_Float16)fmaxf(r4, 0.f), (_Float16)fmaxf(r5, 0.f),
                   (_Float16)fmaxf(r6, 0.f), (_Float16)fmaxf(r7, 0.f)};
        *(half8*)(outh + (size_t)n * 128 + c8) = o;
    }
}

// ---------------- fused attn + softmax + layer-fuse + out-projection: 64 nodes (256 rows) per block ----
// hbase: 4 contiguous layer slabs; row m=node*4+layer at hbase + layer*LSTR + node*128.
__global__ __launch_bounds__(256) void k_afo(const _Float16* __restrict__ hbase, const _Float16* __restrict__ WTatt,
                                             const float* __restrict__ a_att, const _Float16* __restrict__ WoutT,
                                             const float* __restrict__ bout, float* __restrict__ out) {
    __shared__ __align__(16) _Float16 Hs[256][136];   // 69,632 B; stride 272B -> 2-way max on frag reads
    __shared__ __align__(16) _Float16 Fs[64][136];    // 17,408 B
    __shared__ float ssc[256];
    __shared__ float salpha[256];
    const size_t LSTR = (size_t)NNODES * 128;
    int tid = threadIdx.x;
    int n0 = blockIdx.x * 64;

    // ---- stage 256 rows (64 nodes x 4 layers), coalesced per layer slab ----
#pragma unroll
    for (int layer = 0; layer < 4; ++layer) {
#pragma unroll
        for (int i = 0; i < 4; ++i) {
            int idx = i * 256 + tid;            // 0..1023 = 64 nodes * 16 col-chunks
            int no = idx >> 4, col = (idx & 15) * 8;
            int node = n0 + no; if (node > NNODES - 1) node = NNODES - 1;
            half8 v = *(const half8*)(hbase + (size_t)layer * LSTR + (size_t)node * 128 + col);
            *(half8*)&Hs[no * 4 + layer][col] = v;
        }
    }
    __syncthreads();

    int wave = tid >> 6, lane = tid & 63;
    int quad = lane >> 4, l15 = lane & 15;
    int ko = quad * 8;

    // ---- phase A: attention scores for the block's 256 rows ----
    half8 af[4][4];
#pragma unroll
    for (int j = 0; j < 4; ++j) {
        int row = wave * 64 + j * 16 + l15;
#pragma unroll
        for (int kk = 0; kk < 4; ++kk) af[j][kk] = *(const half8*)&Hs[row][kk * 32 + ko];
    }
    float p[4][4];
#pragma unroll
    for (int j = 0; j < 4; ++j)
#pragma unroll
        for (int r = 0; r < 4; ++r) p[j][r] = 0.f;
#pragma unroll
    for (int ct = 0; ct < 8; ++ct) {
        int ncol = ct * 16 + l15;
        const _Float16* Bp = WTatt + ncol * 128 + ko;
        half8 b[4];
#pragma unroll
        for (int kk = 0; kk < 4; ++kk) b[kk] = *(const half8*)(Bp + kk * 32);
        floatx4 acc[4];
#pragma unroll
        for (int j = 0; j < 4; ++j) acc[j] = (floatx4){0.f, 0.f, 0.f, 0.f};
#pragma unroll
        for (int kk = 0; kk < 4; ++kk)
#pragma unroll
            for (int j = 0; j < 4; ++j)
                acc[j] = __builtin_amdgcn_mfma_f32_16x16x32_f16(af[j][kk], b[kk], acc[j], 0, 0, 0);
        float av = a_att[ncol];
#pragma unroll
        for (int j = 0; j < 4; ++j)
#pragma unroll
            for (int r = 0; r < 4; ++r) p[j][r] += av * fast_tanh(acc[j][r]);
    }
#pragma unroll
    for (int j = 0; j < 4; ++j)
#pragma unroll
        for (int r = 0; r < 4; ++r) {
            float v = p[j][r];
            v += __shfl_xor(v, 1); v += __shfl_xor(v, 2);
            v += __shfl_xor(v, 4); v += __shfl_xor(v, 8);
            if (l15 == 0) ssc[wave * 64 + j * 16 + quad * 4 + r] = v;
        }
    __syncthreads();

    // ---- phase B: per-node softmax over 4 layers ----
    if (tid < 64) {
        float s0 = ssc[tid * 4 + 0], s1 = ssc[tid * 4 + 1];
        float s2 = ssc[tid * 4 + 2], s3 = ssc[tid * 4 + 3];
        float mx = fmaxf(fmaxf(s0, s1), fmaxf(s2, s3));
        float e0 = __expf(s0 - mx), e1 = __expf(s1 - mx), e2 = __expf(s2 - mx), e3 = __expf(s3 - mx);
        float inv = 1.0f / (e0 + e1 + e2 + e3);
        salpha[tid * 4 + 0] = e0 * inv; salpha[tid * 4 + 1] = e1 * inv;
        salpha[tid * 4 + 2] = e2 * inv; salpha[tid * 4 + 3] = e3 * inv;
    }
    __syncthreads();

    // ---- phase C: fused = sum_l alpha_l * h_l  (mapping: 16 lanes sweep cols -> 2-way max) ----
#pragma unroll
    for (int pass = 0; pass < 4; ++pass) {
        int no = pass * 16 + (tid >> 4);
        int c8 = (tid & 15) * 8;
        float al0 = salpha[no * 4 + 0], al1 = salpha[no * 4 + 1];
        float al2 = salpha[no * 4 + 2], al3 = salpha[no * 4 + 3];
        half8 h0 = *(const half8*)&Hs[no * 4 + 0][c8];
        half8 h1 = *(const half8*)&Hs[no * 4 + 1][c8];
        half8 h2 = *(const half8*)&Hs[no * 4 + 2][c8];
        half8 h3 = *(const half8*)&Hs[no * 4 + 3][c8];
        half8 f;
#pragma unroll
        for (int u = 0; u < 8; ++u)
            f[u] = (_Float16)(al0 * (float)h0[u] + al1 * (float)h1[u] +
                              al2 * (float)h2[u] + al3 * (float)h3[u]);
        *(half8*)&Fs[no][c8] = f;
    }
    __syncthreads();

    // ---- phase D: out-projection MFMA, 48 padded cols, masked write ----
    half8 ff[4];
    int frow = wave * 16 + l15;
#pragma unroll
    for (int kk = 0; kk < 4; ++kk) ff[kk] = *(const half8*)&Fs[frow][kk * 32 + ko];
#pragma unroll
    for (int ct = 0; ct < 3; ++ct) {
        const _Float16* Bp = WoutT + (ct * 16 + l15) * 128 + ko;
        half8 bw[4];
#pragma unroll
        for (int kk = 0; kk < 4; ++kk) bw[kk] = *(const half8*)(Bp + kk * 32);
        floatx4 acc = (floatx4){0.f, 0.f, 0.f, 0.f};
#pragma unroll
        for (int kk = 0; kk < 4; ++kk)
            acc = __builtin_amdgcn_mfma_f32_16x16x32_f16(ff[kk], bw[kk], acc, 0, 0, 0);
        int col = ct * 16 + l15;
        if (col < NCLASS) {
            float bv = bout[col];
#pragma unroll
            for (int r = 0; r < 4; ++r) {
                int node = n0 + wave * 16 + quad * 4 + r;
                if (node < NNODES) out[(size_t)node * NCLASS + col] = acc[r] + bv;
            }
        }
    }
}

extern "C" void kernel_launch(void* const* d_in, const int* in_sizes, int n_in,
                              void* d_out, int out_size, void* d_ws, size_t ws_size,
                              hipStream_t stream) {
    const float* x     = (const float*)d_in[0];
    const int*   ei    = (const int*)d_in[1];
    const float* convW = (const float*)d_in[2];
    const float* convb = (const float*)d_in[3];
    const float* W_att = (const float*)d_in[4];
    const float* a_att = (const float*)d_in[5];
    const float* W_out = (const float*)d_in[6];
    const float* b_out = (const float*)d_in[7];
    float* out = (float*)d_out;

    char* ws = (char*)d_ws;
    size_t off = 0;
    auto take = [&](size_t nbytes) { char* p = ws + off; off += (nbytes + 255) & ~(size_t)255; return p; };
    float*     dinv    = (float*)take(NNODES * 4);
    int*       cnt     = (int*)take(NNODES * 4);
    int*       rank    = (int*)take(NEDGES * 4);
    int*       offsets = (int*)take((NNODES + 1) * 4);
    int*       bsum    = (int*)take(256 * 4);
    int*       esrc    = (int*)take(NEDGES * 4 + 256);   // +64 ints pad for speculative loads
    _Float16*  WoutT   = (_Float16*)take((size_t)48 * 128 * 2);
    _Float16*  xh      = (_Float16*)take((size_t)NNODES * 128 * 2);
    _Float16*  WT      = (_Float16*)take((size_t)5 * 128 * 128 * 2);
    _Float16*  hWs     = (_Float16*)take((size_t)NNODES * 128 * 2);
    _Float16*  hh[4];
    for (int l = 0; l < 4; ++l) hh[l] = (_Float16*)take((size_t)NNODES * 128 * 2);
    // NOTE: hh slabs are 12,800,000 B each (multiple of 256) -> contiguous; k_afo relies on it.

    const int* src = ei;
    const int* dst = ei + NEDGES;

    hipMemsetAsync(cnt, 0, NNODES * 4, stream);
    k_pre<<<CNTB + F2HB + PREPB + WOUTB, 256, 0, stream>>>(dst, cnt, rank, x, xh, convW, W_att, WT, W_out, WoutT);
    k_bsum<<<NBLK_SCAN, 256, 0, stream>>>(cnt, bsum);
    k_offsets<<<NBLK_SCAN, 256, 0, stream>>>(cnt, bsum, offsets, dinv);
    k_fillgemm<<<GEMMB + CNTB, 256, 0, stream>>>(src, dst, offsets, rank, esrc, xh, WT, dinv, hWs);

    k_aggregate<<<NNODES / 8, 256, 0, stream>>>(hWs, offsets, esrc, dinv, convb + 0 * 128, hh[0]);
    for (int l = 1; l < 4; ++l) {
        k_gemm_f16<<<GEMMB, 256, 0, stream>>>(hh[l - 1], WT + l * 16384, dinv, hWs);
        k_aggregate<<<NNODES / 8, 256, 0, stream>>>(hWs, offsets, esrc, dinv, convb + l * 128, hh[l]);
    }
    k_afo<<<AFOB, 256, 0, stream>>>(hh[0], WT + 4 * 16384, a_att, WoutT, b_out, out);
}